// Round 16
// baseline (126.104 us; speedup 1.0000x reference)
//
#include <hip/hip_runtime.h>

typedef float f32x4 __attribute__((ext_vector_type(4)));
typedef __bf16 bf16x8_t __attribute__((ext_vector_type(8)));
typedef __bf16 bf16x4_t __attribute__((ext_vector_type(4)));
typedef unsigned int u32x2 __attribute__((ext_vector_type(2)));

#define GLOAD16(gptr, lptr)                                                        \
  __builtin_amdgcn_global_load_lds((const __attribute__((address_space(1))) void*)(gptr), \
                                   (__attribute__((address_space(3))) void*)(lptr), 16, 0, 0)

__device__ inline float fexp2(float x) {
  float r;
  asm("v_exp_f32 %0, %1" : "=v"(r) : "v"(x));
  return r;
}

union VFu { bf16x8_t v8; u32x2 w[2]; };

#define TRR(d, B, OFF) \
  asm volatile("ds_read_b64_tr_b16 %0, %1 offset:" OFF : "=v"(d) : "v"(B))

// ---------------- merged prep kernel ----------------
__global__ __launch_bounds__(256) void k_prep(const float* __restrict__ x,
                                              const float* __restrict__ wq,
                                              const float* __restrict__ wk,
                                              const float* __restrict__ wv,
                                              const float* __restrict__ wo,
                                              const float* __restrict__ bq,
                                              const float* __restrict__ bk,
                                              const float* __restrict__ bv,
                                              __bf16* __restrict__ xb,
                                              __bf16* __restrict__ wb1,
                                              __bf16* __restrict__ wb2,
                                              float* __restrict__ b1) {
  __shared__ __bf16 tr[64][64];
  int bid = blockIdx.x, t = threadIdx.x;
  if (bid < 4096) {
    int i = bid * 256 + t;
    float4 a = reinterpret_cast<const float4*>(x)[i];
    bf16x4_t o;
    o[0] = (__bf16)a.x; o[1] = (__bf16)a.y; o[2] = (__bf16)a.z; o[3] = (__bf16)a.w;
    reinterpret_cast<bf16x4_t*>(xb)[i] = o;
  } else if (bid < 4864) {
    int k = bid - 4096;
    int dt = k & 15, h = (k >> 4) & 15, p = k >> 8;
    const float* W = (p == 0) ? wq : (p == 1) ? wk : wv;
#pragma unroll
    for (int i = 0; i < 4; ++i) {
      int fl = i * 1024 + t * 4;
      int dd = fl >> 6, e = fl & 63;
      float4 a = *reinterpret_cast<const float4*>(W + ((size_t)(h * 1024 + dt * 64 + dd) * 64 + e));
      tr[e + 0][dd] = (__bf16)a.x; tr[e + 1][dd] = (__bf16)a.y;
      tr[e + 2][dd] = (__bf16)a.z; tr[e + 3][dd] = (__bf16)a.w;
    }
    __syncthreads();
#pragma unroll
    for (int i = 0; i < 2; ++i) {
      int ch = i * 256 + t;
      int e = ch >> 3, c8 = ch & 7;
      *reinterpret_cast<bf16x8_t*>(wb1 + ((size_t)(p * 1024 + h * 64 + e) * 1024 + dt * 64 + c8 * 8)) =
          *reinterpret_cast<const bf16x8_t*>(&tr[e][c8 * 8]);
    }
  } else if (bid < 5120) {
    int k = bid - 4864;
    int nt = k & 15, h = k >> 4;
#pragma unroll
    for (int i = 0; i < 4; ++i) {
      int fl = i * 1024 + t * 4;
      int e = fl >> 6, nn = fl & 63;
      float4 a = *reinterpret_cast<const float4*>(wo + ((size_t)(h * 64 + e) * 1024 + nt * 64 + nn));
      tr[nn + 0][e] = (__bf16)a.x; tr[nn + 1][e] = (__bf16)a.y;
      tr[nn + 2][e] = (__bf16)a.z; tr[nn + 3][e] = (__bf16)a.w;
    }
    __syncthreads();
#pragma unroll
    for (int i = 0; i < 2; ++i) {
      int ch = i * 256 + t;
      int nn = ch >> 3, c8 = ch & 7;
      *reinterpret_cast<bf16x8_t*>(wb2 + ((size_t)(nt * 64 + nn) * 1024 + h * 64 + c8 * 8)) =
          *reinterpret_cast<const bf16x8_t*>(&tr[nn][c8 * 8]);
    }
  } else {
    int n = (bid - 5120) * 256 + t;
    if (n < 3072) {
      int p = n >> 10, he = n & 1023;
      const float* s = (p == 0) ? bq : (p == 1) ? bk : bv;
      b1[n] = s[he];
    }
  }
}

// ---------------- GEMM: BK=32, 2-phase double-buffered staging ----------------
// Loop: issue STAGE(next) -> MFMA(cur) -> __syncthreads() (implicit vmcnt(0)
// drains the prefetch AFTER compute). One barrier/iter; staging hides under MFMA.
template <typename OutT, int MODE, int MT, int NT>
__global__ __launch_bounds__(256) void k_gemm(const __bf16* __restrict__ A,
                                              const __bf16* __restrict__ Bt,
                                              const float* __restrict__ bias,
                                              OutT* __restrict__ C, int N, int K) {
  __shared__ __bf16 As[2][MT * 32];
  __shared__ __bf16 Bs[2][NT * 32];
  constexpr int MI = MT / 32;
  constexpr int NR = NT / 32;
  constexpr int AI = MT / 64;   // staging iters: MT*4 loads / 256 threads
  constexpr int BI = NT / 64 > 0 ? NT / 64 : 1;
  int t = threadIdx.x, l = t & 63;
  int lo = l & 15, hi = l >> 4;
  int w = t >> 6;
  int bid = blockIdx.x;
  int xcd = bid & 7, loc = bid >> 3;
  int xc = N / NT;
  int rx = (int)gridDim.x / (8 * xc);
  int yy = loc / xc;
  int xx = loc - yy * xc;
  int m0 = (xcd * rx + yy) * MT, n0 = xx * NT;
  int wm = (w >> 1) * (MT / 2), wn = (w & 1) * (NT / 2);
  f32x4 acc[MI][NR] = {};

#define STAGE_G(buf, k0v)                                                               \
  {                                                                                     \
    _Pragma("unroll") for (int it = 0; it < AI; ++it) {                                 \
      int idx = it * 256 + t;                                                           \
      int row = idx >> 2, c = idx & 3;                                                  \
      int cs = (c ^ (row & 3)) * 8;                                                     \
      GLOAD16(A + (size_t)(m0 + row) * K + (k0v) + cs,                                  \
              (char*)As[buf] + (it * 256 + (t & ~63)) * 16);                            \
    }                                                                                   \
    _Pragma("unroll") for (int it = 0; it < BI; ++it) {                                 \
      int idx = it * 256 + t;                                                           \
      int row = idx >> 2, c = idx & 3;                                                  \
      int cs = (c ^ (row & 3)) * 8;                                                     \
      GLOAD16(Bt + (size_t)(n0 + row) * K + (k0v) + cs,                                 \
              (char*)Bs[buf] + (it * 256 + (t & ~63)) * 16);                            \
    }                                                                                   \
  }

  STAGE_G(0, 0);
  __syncthreads();
  for (int k0 = 0; k0 < K; k0 += 32) {
    int cur = (k0 >> 5) & 1;
    if (k0 + 32 < K) STAGE_G(cur ^ 1, k0 + 32);
    bf16x8_t af[MI], bfr[NR];
#pragma unroll
    for (int mi = 0; mi < MI; ++mi) {
      int row = wm + mi * 16 + lo;
      af[mi] = *reinterpret_cast<const bf16x8_t*>(
          (char*)As[cur] + row * 64 + ((hi ^ (row & 3)) << 4));
    }
#pragma unroll
    for (int ni = 0; ni < NR; ++ni) {
      int row = wn + ni * 16 + lo;
      bfr[ni] = *reinterpret_cast<const bf16x8_t*>(
          (char*)Bs[cur] + row * 64 + ((hi ^ (row & 3)) << 4));
    }
#pragma unroll
    for (int mi = 0; mi < MI; ++mi)
#pragma unroll
      for (int ni = 0; ni < NR; ++ni)
        acc[mi][ni] = __builtin_amdgcn_mfma_f32_16x16x32_bf16(af[mi], bfr[ni], acc[mi][ni], 0, 0, 0);
    __syncthreads();
  }
#undef STAGE_G
  float qs = (MODE == 1 && n0 < 1024) ? 0.18033688f : 1.0f;
#pragma unroll
  for (int ni = 0; ni < NR; ++ni) {
    int n = n0 + wn + ni * 16 + lo;
    float bv = bias[n];
    int p = n >> 10, hh = (n >> 6) & 15, e = n & 63;
#pragma unroll
    for (int mi = 0; mi < MI; ++mi) {
#pragma unroll
      for (int r = 0; r < 4; ++r) {
        int m = m0 + wm + mi * 16 + hi * 4 + r;
        if (MODE == 0) {
          C[(size_t)m * N + n] = (OutT)(acc[mi][ni][r] + bv);
        } else {
          int b = m >> 11, sr = m & 2047;
          C[(size_t)(p * 32 + b * 16 + hh) * 131072 + sr * 64 + e] =
              (OutT)((acc[mi][ni][r] + bv) * qs);
        }
      }
    }
  }
}

// ---------------- causal flash attention (v15: uniform 33-tile pair blocks) ----
__global__ __launch_bounds__(256, 4) void k_attn(const __bf16* __restrict__ QKVh,
                                                 __bf16* __restrict__ Z) {
  __shared__ __bf16 Ks[2][64 * 64];  // row-swizzled: chunk ^= row&7
  __shared__ __bf16 Vs[2][64 * 64];  // subtiled for tr_b16 reads
  __shared__ __bf16 Ps[64 * 64];     // wave-private 16-row bands
  int t = threadIdx.x, l = t & 63, w = t >> 6;
  int lo = l & 15, hi = l >> 4;
  int bid = blockIdx.x;
  int xcd = bid & 7, kk = bid >> 3;
  int pr = kk & 15, bhl = kk >> 4;   // pair index 0..15, bh-local 0..3
  int bh = xcd * 4 + bhl;
  int b = bh >> 4, h = bh & 15;

  const __bf16* Qbase = QKVh + (size_t)bh * 131072;
  const __bf16* Kbase = QKVh + (size_t)(32 + bh) * 131072;
  const __bf16* Vbase = QKVh + (size_t)(64 + bh) * 131072;

  // per-thread staging source offsets (tile-invariant)
  int kSrc[2], vSrc[2];
#pragma unroll
  for (int it = 0; it < 2; ++it) {
    int idx = it * 256 + t;
    int row = idx >> 3, c = idx & 7;
    kSrc[it] = row * 64 + ((c ^ (row & 7)) * 8);
    int kv = ((idx >> 1) & 3) | (((idx >> 5) & 1) << 2) | (((idx >> 3) & 3) << 3) |
             (((idx >> 8) & 1) << 5);
    int e0s = ((idx & 1) << 3) | (((idx >> 6) & 3) << 4);
    vSrc[it] = kv * 64 + e0s;
  }

#define STAGE_KV(buf, tile)                                                             \
  {                                                                                     \
    GLOAD16(Kbase + (tile) * 4096 + kSrc[0], (char*)Ks[buf] + (t & ~63) * 16);          \
    GLOAD16(Kbase + (tile) * 4096 + kSrc[1], (char*)Ks[buf] + 4096 + (t & ~63) * 16);   \
    GLOAD16(Vbase + (tile) * 4096 + vSrc[0], (char*)Vs[buf] + (t & ~63) * 16);          \
    GLOAD16(Vbase + (tile) * 4096 + vSrc[1], (char*)Vs[buf] + 4096 + (t & ~63) * 16);   \
  }

#pragma unroll 1
  for (int half = 0; half < 2; ++half) {
    int g = half ? pr : (31 - pr);   // long half first (B-half prefix re-hits L2)
    int qbase = g * 64 + w * 16;
    int ntH = g + 1;

    bf16x8_t qf[2];
    {
      const __bf16* qptr = Qbase + (qbase + lo) * 64;
      qf[0] = *reinterpret_cast<const bf16x8_t*>(qptr + hi * 8);
      qf[1] = *reinterpret_cast<const bf16x8_t*>(qptr + 32 + hi * 8);
    }

    f32x4 zacc[4] = {};
    float lsum = 0.f;
    float mrow = -1e30f;

    // prologue for this half
    STAGE_KV(0, 0);
    __syncthreads();

    for (int tile = 0; tile < ntH; ++tile) {
      int cur = tile & 1, kv0 = tile * 64;
      bool havenext = (tile + 1 < ntH);
      if (havenext) {
        STAGE_KV(cur ^ 1, tile + 1);
        __builtin_amdgcn_sched_barrier(0);
      }
      // QK^T swapped: s[cb][r] = S^T[kv=cb*16+hi*4+r][q=lo]  (Q pre-scaled)
      f32x4 s[4] = {};
      __builtin_amdgcn_s_setprio(1);
#pragma unroll
      for (int cb = 0; cb < 4; ++cb) {
        int krow = cb * 16 + lo;
        const char* kp = (const char*)Ks[cur] + krow * 128;
        bf16x8_t kf0 = *reinterpret_cast<const bf16x8_t*>(kp + ((hi ^ (krow & 7)) << 4));
        bf16x8_t kf1 = *reinterpret_cast<const bf16x8_t*>(kp + (((4 + hi) ^ (krow & 7)) << 4));
        s[cb] = __builtin_amdgcn_mfma_f32_16x16x32_bf16(kf0, qf[0], s[cb], 0, 0, 0);
        s[cb] = __builtin_amdgcn_mfma_f32_16x16x32_bf16(kf1, qf[1], s[cb], 0, 0, 0);
      }
      __builtin_amdgcn_s_setprio(0);
      // softmax (exp2 domain), defer-max THR=8, per-lane lsum
      {
        int qabs = qbase + lo;
        if (tile == ntH - 1) {  // wave-uniform: diagonal tile only
#pragma unroll
          for (int cb = 0; cb < 4; ++cb)
#pragma unroll
            for (int r = 0; r < 4; ++r)
              if (kv0 + cb * 16 + hi * 4 + r > qabs) s[cb][r] = -1e30f;
        }
        float mt = -1e30f;
#pragma unroll
        for (int cb = 0; cb < 4; ++cb) {
          float m01 = fmaxf(s[cb][0], s[cb][1]);
          float m23 = fmaxf(s[cb][2], s[cb][3]);
          mt = fmaxf(mt, fmaxf(m01, m23));
        }
        mt = fmaxf(mt, __shfl_xor(mt, 16));
        mt = fmaxf(mt, __shfl_xor(mt, 32));
        if (!__all(mt - mrow <= 8.0f)) {
          float mnew = fmaxf(mrow, mt);
          float alpha = fexp2(mrow - mnew);
          mrow = mnew;
          lsum *= alpha;
#pragma unroll
          for (int r = 0; r < 4; ++r) {
            float at = __shfl(alpha, hi * 4 + r);
#pragma unroll
            for (int e0 = 0; e0 < 4; ++e0) zacc[e0][r] *= at;
          }
        }
        float psum = 0.f;
        int prow = w * 16 + lo;
        char* prp = (char*)Ps + prow * 128 + (hi & 1) * 8;
        int rsw = prow & 7;
#pragma unroll
        for (int cb = 0; cb < 4; ++cb) {
          bf16x4_t pp;
#pragma unroll
          for (int r = 0; r < 4; ++r) {
            float p = fexp2(s[cb][r] - mrow);
            psum += p;
            pp[r] = (__bf16)p;
          }
          *reinterpret_cast<bf16x4_t*>(prp + (((cb * 2 + (hi >> 1)) ^ rsw) << 4)) = pp;
        }
        lsum += psum;
      }
      // PV: single pass, counted lgkmcnt (pf reads + 16 tr-reads in flight)
      __builtin_amdgcn_s_setprio(1);
      {
        const __attribute__((address_space(3))) char* vb =
            (const __attribute__((address_space(3))) char*)((char*)Vs[cur]) + l * 8;
        int arow = w * 16 + lo;
        char* psb = (char*)Ps + arow * 128;
        const __attribute__((address_space(3))) char* pp0 =
            (const __attribute__((address_space(3))) char*)(psb + ((hi ^ (arow & 7)) << 4));
        const __attribute__((address_space(3))) char* pp1 =
            (const __attribute__((address_space(3))) char*)(psb + (((4 + hi) ^ (arow & 7)) << 4));
        bf16x8_t pf0, pf1;
        asm volatile("ds_read_b128 %0, %1" : "=v"(pf0) : "v"(pp0) : "memory");
        asm volatile("ds_read_b128 %0, %1" : "=v"(pf1) : "v"(pp1) : "memory");
        VFu u[8];
        TRR(u[0].w[0], vb, "0");    TRR(u[0].w[1], vb, "512");
        TRR(u[1].w[0], vb, "1024"); TRR(u[1].w[1], vb, "1536");
        TRR(u[2].w[0], vb, "2048"); TRR(u[2].w[1], vb, "2560");
        TRR(u[3].w[0], vb, "3072"); TRR(u[3].w[1], vb, "3584");
        TRR(u[4].w[0], vb, "4096"); TRR(u[4].w[1], vb, "4608");
        TRR(u[5].w[0], vb, "5120"); TRR(u[5].w[1], vb, "5632");
        TRR(u[6].w[0], vb, "6144"); TRR(u[6].w[1], vb, "6656");
        TRR(u[7].w[0], vb, "7168"); TRR(u[7].w[1], vb, "7680");
        asm volatile("s_waitcnt lgkmcnt(8)" ::: "memory");
        __builtin_amdgcn_sched_barrier(0);
        zacc[0] = __builtin_amdgcn_mfma_f32_16x16x32_bf16(pf0, u[0].v8, zacc[0], 0, 0, 0);
        zacc[1] = __builtin_amdgcn_mfma_f32_16x16x32_bf16(pf0, u[1].v8, zacc[1], 0, 0, 0);
        zacc[2] = __builtin_amdgcn_mfma_f32_16x16x32_bf16(pf0, u[2].v8, zacc[2], 0, 0, 0);
        zacc[3] = __builtin_amdgcn_mfma_f32_16x16x32_bf16(pf0, u[3].v8, zacc[3], 0, 0, 0);
        asm volatile("s_waitcnt lgkmcnt(0)" ::: "memory");
        __builtin_amdgcn_sched_barrier(0);
        zacc[0] = __builtin_amdgcn_mfma_f32_16x16x32_bf16(pf1, u[4].v8, zacc[0], 0, 0, 0);
        zacc[1] = __builtin_amdgcn_mfma_f32_16x16x32_bf16(pf1, u[5].v8, zacc[1], 0, 0, 0);
        zacc[2] = __builtin_amdgcn_mfma_f32_16x16x32_bf16(pf1, u[6].v8, zacc[2], 0, 0, 0);
        zacc[3] = __builtin_amdgcn_mfma_f32_16x16x32_bf16(pf1, u[7].v8, zacc[3], 0, 0, 0);
      }
      __builtin_amdgcn_s_setprio(0);
      __syncthreads();
    }

    // epilogue for this half: reduce lsum across hi-groups, normalize, store
    float lt = lsum;
    lt += __shfl_xor(lt, 16);
    lt += __shfl_xor(lt, 32);
    float inv = 1.0f / lt;
#pragma unroll
    for (int r = 0; r < 4; ++r) {
      float lv = __shfl(inv, hi * 4 + r);
      size_t row = (size_t)(b * 2048 + qbase + hi * 4 + r);
#pragma unroll
      for (int e0 = 0; e0 < 4; ++e0)
        Z[row * 1024 + h * 64 + e0 * 16 + lo] = (__bf16)(zacc[e0][r] * lv);
    }
    __syncthreads();  // all waves done with LDS before next half's staging
  }
#undef STAGE_KV
}

// ---------------- launch ----------------

extern "C" void kernel_launch(void* const* d_in, const int* in_sizes, int n_in,
                              void* d_out, int out_size, void* d_ws, size_t ws_size,
                              hipStream_t stream) {
  const float* x  = (const float*)d_in[0];
  const float* wq = (const float*)d_in[1];
  const float* wk = (const float*)d_in[2];
  const float* wv = (const float*)d_in[3];
  const float* wo = (const float*)d_in[4];
  const float* bq = (const float*)d_in[5];
  const float* bk = (const float*)d_in[6];
  const float* bv = (const float*)d_in[7];
  const float* bo = (const float*)d_in[8];
  float* out = (float*)d_out;

  char* ws = (char*)d_ws;
  __bf16* Xb   = (__bf16*)(ws);                //  8388608 B  [4096][1024]
  __bf16* WB1  = (__bf16*)(ws + 8388608);      //  6291456 B  [3072][1024]
  float*  B1   = (float*)(ws + 14680064);      //    12288 B  [3072]
  __bf16* WB2  = (__bf16*)(ws + 14692352);     //  2097152 B  [1024][1024]
  __bf16* QKVh = (__bf16*)(ws + 16789504);     // 25165824 B  [3][32][2048][64]
  __bf16* Zb   = Xb;                           // overlay: X dead after GEMM1

  k_prep<<<5132, 256, 0, stream>>>(x, wq, wk, wv, wo, bq, bk, bv, Xb, WB1, WB2, B1);
  k_gemm<__bf16, 1, 128, 64><<<1536, 256, 0, stream>>>(Xb, WB1, B1, QKVh, 3072, 1024);
  k_attn<<<512, 256, 0, stream>>>(QKVh, Zb);
  k_gemm<float, 0, 64, 64><<<1024, 256, 0, stream>>>(Zb, WB2, bo, out, 1024, 1024);
}

// Round 17
// 114.355 us; speedup vs baseline: 1.1027x; 1.1027x over previous
//
#include <hip/hip_runtime.h>

typedef float f32x4 __attribute__((ext_vector_type(4)));
typedef __bf16 bf16x8_t __attribute__((ext_vector_type(8)));
typedef __bf16 bf16x4_t __attribute__((ext_vector_type(4)));
typedef unsigned int u32x2 __attribute__((ext_vector_type(2)));

#define GLOAD16(gptr, lptr)                                                        \
  __builtin_amdgcn_global_load_lds((const __attribute__((address_space(1))) void*)(gptr), \
                                   (__attribute__((address_space(3))) void*)(lptr), 16, 0, 0)

__device__ inline float fexp2(float x) {
  float r;
  asm("v_exp_f32 %0, %1" : "=v"(r) : "v"(x));
  return r;
}

union VFu { bf16x8_t v8; u32x2 w[2]; };

#define TRR(d, B, OFF) \
  asm volatile("ds_read_b64_tr_b16 %0, %1 offset:" OFF : "=v"(d) : "v"(B))

// ---------------- merged prep kernel ----------------
__global__ __launch_bounds__(256) void k_prep(const float* __restrict__ x,
                                              const float* __restrict__ wq,
                                              const float* __restrict__ wk,
                                              const float* __restrict__ wv,
                                              const float* __restrict__ wo,
                                              const float* __restrict__ bq,
                                              const float* __restrict__ bk,
                                              const float* __restrict__ bv,
                                              __bf16* __restrict__ xb,
                                              __bf16* __restrict__ wb1,
                                              __bf16* __restrict__ wb2,
                                              float* __restrict__ b1) {
  __shared__ __bf16 tr[64][64];
  int bid = blockIdx.x, t = threadIdx.x;
  if (bid < 4096) {
    int i = bid * 256 + t;
    float4 a = reinterpret_cast<const float4*>(x)[i];
    bf16x4_t o;
    o[0] = (__bf16)a.x; o[1] = (__bf16)a.y; o[2] = (__bf16)a.z; o[3] = (__bf16)a.w;
    reinterpret_cast<bf16x4_t*>(xb)[i] = o;
  } else if (bid < 4864) {
    int k = bid - 4096;
    int dt = k & 15, h = (k >> 4) & 15, p = k >> 8;
    const float* W = (p == 0) ? wq : (p == 1) ? wk : wv;
#pragma unroll
    for (int i = 0; i < 4; ++i) {
      int fl = i * 1024 + t * 4;
      int dd = fl >> 6, e = fl & 63;
      float4 a = *reinterpret_cast<const float4*>(W + ((size_t)(h * 1024 + dt * 64 + dd) * 64 + e));
      tr[e + 0][dd] = (__bf16)a.x; tr[e + 1][dd] = (__bf16)a.y;
      tr[e + 2][dd] = (__bf16)a.z; tr[e + 3][dd] = (__bf16)a.w;
    }
    __syncthreads();
#pragma unroll
    for (int i = 0; i < 2; ++i) {
      int ch = i * 256 + t;
      int e = ch >> 3, c8 = ch & 7;
      *reinterpret_cast<bf16x8_t*>(wb1 + ((size_t)(p * 1024 + h * 64 + e) * 1024 + dt * 64 + c8 * 8)) =
          *reinterpret_cast<const bf16x8_t*>(&tr[e][c8 * 8]);
    }
  } else if (bid < 5120) {
    int k = bid - 4864;
    int nt = k & 15, h = k >> 4;
#pragma unroll
    for (int i = 0; i < 4; ++i) {
      int fl = i * 1024 + t * 4;
      int e = fl >> 6, nn = fl & 63;
      float4 a = *reinterpret_cast<const float4*>(wo + ((size_t)(h * 64 + e) * 1024 + nt * 64 + nn));
      tr[nn + 0][e] = (__bf16)a.x; tr[nn + 1][e] = (__bf16)a.y;
      tr[nn + 2][e] = (__bf16)a.z; tr[nn + 3][e] = (__bf16)a.w;
    }
    __syncthreads();
#pragma unroll
    for (int i = 0; i < 2; ++i) {
      int ch = i * 256 + t;
      int nn = ch >> 3, c8 = ch & 7;
      *reinterpret_cast<bf16x8_t*>(wb2 + ((size_t)(nt * 64 + nn) * 1024 + h * 64 + c8 * 8)) =
          *reinterpret_cast<const bf16x8_t*>(&tr[nn][c8 * 8]);
    }
  } else {
    int n = (bid - 5120) * 256 + t;
    if (n < 3072) {
      int p = n >> 10, he = n & 1023;
      const float* s = (p == 0) ? bq : (p == 1) ? bk : bv;
      b1[n] = s[he];
    }
  }
}

// ---------------- GEMM template: BK=64, tile MT x NT, XCD-chunked 1D grid ----
template <typename OutT, int MODE, int MT, int NT>
__global__ __launch_bounds__(256) void k_gemm(const __bf16* __restrict__ A,
                                              const __bf16* __restrict__ Bt,
                                              const float* __restrict__ bias,
                                              OutT* __restrict__ C, int N, int K) {
  __shared__ __bf16 As[MT * 64];
  __shared__ __bf16 Bs[NT * 64];
  constexpr int MI = MT / 32;
  constexpr int NR = NT / 32;
  constexpr int AI = MT / 32;
  constexpr int BI = NT / 32;
  int t = threadIdx.x, l = t & 63;
  int lo = l & 15, hi = l >> 4;
  int w = t >> 6;
  int bid = blockIdx.x;
  int xcd = bid & 7, loc = bid >> 3;
  int xc = N / NT;
  int rx = (int)gridDim.x / (8 * xc);
  int yy = loc / xc;
  int xx = loc - yy * xc;
  int m0 = (xcd * rx + yy) * MT, n0 = xx * NT;
  int wm = (w >> 1) * (MT / 2), wn = (w & 1) * (NT / 2);
  f32x4 acc[MI][NR] = {};
  for (int k0 = 0; k0 < K; k0 += 64) {
    __syncthreads();
#pragma unroll
    for (int it = 0; it < AI; ++it) {
      int idx = it * 256 + t;
      int row = idx >> 3, c = idx & 7;
      int cs = (c ^ (row & 7)) * 8;
      GLOAD16(A + (size_t)(m0 + row) * K + k0 + cs, (char*)As + (it * 256 + (t & ~63)) * 16);
    }
#pragma unroll
    for (int it = 0; it < BI; ++it) {
      int idx = it * 256 + t;
      int row = idx >> 3, c = idx & 7;
      int cs = (c ^ (row & 7)) * 8;
      GLOAD16(Bt + (size_t)(n0 + row) * K + k0 + cs, (char*)Bs + (it * 256 + (t & ~63)) * 16);
    }
    __syncthreads();
#pragma unroll
    for (int kc = 0; kc < 2; ++kc) {
      bf16x8_t af[MI], bfr[NR];
#pragma unroll
      for (int mi = 0; mi < MI; ++mi) {
        int row = wm + mi * 16 + lo;
        af[mi] = *reinterpret_cast<const bf16x8_t*>(
            (char*)As + row * 128 + (((kc * 4 + hi) ^ (row & 7)) << 4));
      }
#pragma unroll
      for (int ni = 0; ni < NR; ++ni) {
        int row = wn + ni * 16 + lo;
        bfr[ni] = *reinterpret_cast<const bf16x8_t*>(
            (char*)Bs + row * 128 + (((kc * 4 + hi) ^ (row & 7)) << 4));
      }
#pragma unroll
      for (int mi = 0; mi < MI; ++mi)
#pragma unroll
        for (int ni = 0; ni < NR; ++ni)
          acc[mi][ni] = __builtin_amdgcn_mfma_f32_16x16x32_bf16(af[mi], bfr[ni], acc[mi][ni], 0, 0, 0);
    }
  }
  float qs = (MODE == 1 && n0 < 1024) ? 0.18033688f : 1.0f;
#pragma unroll
  for (int ni = 0; ni < NR; ++ni) {
    int n = n0 + wn + ni * 16 + lo;
    float bv = bias[n];
    int p = n >> 10, hh = (n >> 6) & 15, e = n & 63;
#pragma unroll
    for (int mi = 0; mi < MI; ++mi) {
#pragma unroll
      for (int r = 0; r < 4; ++r) {
        int m = m0 + wm + mi * 16 + hi * 4 + r;
        if (MODE == 0) {
          C[(size_t)m * N + n] = (OutT)(acc[mi][ni][r] + bv);
        } else {
          int b = m >> 11, sr = m & 2047;
          C[(size_t)(p * 32 + b * 16 + hh) * 131072 + sr * 64 + e] =
              (OutT)((acc[mi][ni][r] + bv) * qs);
        }
      }
    }
  }
}

// ---------------- causal flash attention (v17: uniform pairs + x-half prefetch) --
// Block = pair (31-pr, pr) of 64-row q-groups, processed sequentially; half 0's
// last tile prefetches half 1's tile 0 (buffer parity carried via bufbase).
// 512 blocks = 2/CU, 40KB LDS.
__global__ __launch_bounds__(256, 4) void k_attn(const __bf16* __restrict__ QKVh,
                                                 __bf16* __restrict__ Z) {
  __shared__ __bf16 Ks[2][64 * 64];  // row-swizzled: chunk ^= row&7
  __shared__ __bf16 Vs[2][64 * 64];  // subtiled for tr_b16 reads
  __shared__ __bf16 Ps[64 * 64];     // wave-private 16-row bands
  int t = threadIdx.x, l = t & 63, w = t >> 6;
  int lo = l & 15, hi = l >> 4;
  int bid = blockIdx.x;
  int xcd = bid & 7, kk = bid >> 3;
  int pr = kk & 15, bhl = kk >> 4;   // pair index 0..15, bh-local 0..3
  int bh = xcd * 4 + bhl;
  int b = bh >> 4, h = bh & 15;

  const __bf16* Qbase = QKVh + (size_t)bh * 131072;
  const __bf16* Kbase = QKVh + (size_t)(32 + bh) * 131072;
  const __bf16* Vbase = QKVh + (size_t)(64 + bh) * 131072;

  // per-thread staging source offsets (tile-invariant)
  int kSrc[2], vSrc[2];
#pragma unroll
  for (int it = 0; it < 2; ++it) {
    int idx = it * 256 + t;
    int row = idx >> 3, c = idx & 7;
    kSrc[it] = row * 64 + ((c ^ (row & 7)) * 8);
    int kv = ((idx >> 1) & 3) | (((idx >> 5) & 1) << 2) | (((idx >> 3) & 3) << 3) |
             (((idx >> 8) & 1) << 5);
    int e0s = ((idx & 1) << 3) | (((idx >> 6) & 3) << 4);
    vSrc[it] = kv * 64 + e0s;
  }

#define STAGE_KV(buf, tile)                                                             \
  {                                                                                     \
    GLOAD16(Kbase + (tile) * 4096 + kSrc[0], (char*)Ks[buf] + (t & ~63) * 16);          \
    GLOAD16(Kbase + (tile) * 4096 + kSrc[1], (char*)Ks[buf] + 4096 + (t & ~63) * 16);   \
    GLOAD16(Vbase + (tile) * 4096 + vSrc[0], (char*)Vs[buf] + (t & ~63) * 16);          \
    GLOAD16(Vbase + (tile) * 4096 + vSrc[1], (char*)Vs[buf] + 4096 + (t & ~63) * 16);   \
  }

  int bufbase = 0;
  // prologue for half 0
  STAGE_KV(0, 0);
  __syncthreads();

#pragma unroll 1
  for (int half = 0; half < 2; ++half) {
    int g = half ? pr : (31 - pr);   // long half first (B-half prefix re-hits L2)
    int qbase = g * 64 + w * 16;
    int ntH = g + 1;

    bf16x8_t qf[2];
    {
      const __bf16* qptr = Qbase + (qbase + lo) * 64;
      qf[0] = *reinterpret_cast<const bf16x8_t*>(qptr + hi * 8);
      qf[1] = *reinterpret_cast<const bf16x8_t*>(qptr + 32 + hi * 8);
    }

    f32x4 zacc[4] = {};
    float lsum = 0.f;
    float mrow = -1e30f;

    for (int tile = 0; tile < ntH; ++tile) {
      int cur = (tile + bufbase) & 1, kv0 = tile * 64;
      bool havenext = (tile + 1 < ntH);
      if (havenext) {
        STAGE_KV(cur ^ 1, tile + 1);
        __builtin_amdgcn_sched_barrier(0);
      } else if (half == 0) {
        STAGE_KV(cur ^ 1, 0);  // prefetch half 1's tile 0
        __builtin_amdgcn_sched_barrier(0);
      }
      // QK^T swapped: s[cb][r] = S^T[kv=cb*16+hi*4+r][q=lo]  (Q pre-scaled)
      f32x4 s[4] = {};
      __builtin_amdgcn_s_setprio(1);
#pragma unroll
      for (int cb = 0; cb < 4; ++cb) {
        int krow = cb * 16 + lo;
        const char* kp = (const char*)Ks[cur] + krow * 128;
        bf16x8_t kf0 = *reinterpret_cast<const bf16x8_t*>(kp + ((hi ^ (krow & 7)) << 4));
        bf16x8_t kf1 = *reinterpret_cast<const bf16x8_t*>(kp + (((4 + hi) ^ (krow & 7)) << 4));
        s[cb] = __builtin_amdgcn_mfma_f32_16x16x32_bf16(kf0, qf[0], s[cb], 0, 0, 0);
        s[cb] = __builtin_amdgcn_mfma_f32_16x16x32_bf16(kf1, qf[1], s[cb], 0, 0, 0);
      }
      __builtin_amdgcn_s_setprio(0);
      // softmax (exp2 domain), defer-max THR=8, per-lane lsum
      {
        int qabs = qbase + lo;
        if (tile == ntH - 1) {  // wave-uniform: diagonal tile only
#pragma unroll
          for (int cb = 0; cb < 4; ++cb)
#pragma unroll
            for (int r = 0; r < 4; ++r)
              if (kv0 + cb * 16 + hi * 4 + r > qabs) s[cb][r] = -1e30f;
        }
        float mt = -1e30f;
#pragma unroll
        for (int cb = 0; cb < 4; ++cb) {
          float m01 = fmaxf(s[cb][0], s[cb][1]);
          float m23 = fmaxf(s[cb][2], s[cb][3]);
          mt = fmaxf(mt, fmaxf(m01, m23));
        }
        mt = fmaxf(mt, __shfl_xor(mt, 16));
        mt = fmaxf(mt, __shfl_xor(mt, 32));
        if (!__all(mt - mrow <= 8.0f)) {
          float mnew = fmaxf(mrow, mt);
          float alpha = fexp2(mrow - mnew);
          mrow = mnew;
          lsum *= alpha;
#pragma unroll
          for (int r = 0; r < 4; ++r) {
            float at = __shfl(alpha, hi * 4 + r);
#pragma unroll
            for (int e0 = 0; e0 < 4; ++e0) zacc[e0][r] *= at;
          }
        }
        float psum = 0.f;
        int prow = w * 16 + lo;
        char* prp = (char*)Ps + prow * 128 + (hi & 1) * 8;
        int rsw = prow & 7;
#pragma unroll
        for (int cb = 0; cb < 4; ++cb) {
          bf16x4_t pp;
#pragma unroll
          for (int r = 0; r < 4; ++r) {
            float p = fexp2(s[cb][r] - mrow);
            psum += p;
            pp[r] = (__bf16)p;
          }
          *reinterpret_cast<bf16x4_t*>(prp + (((cb * 2 + (hi >> 1)) ^ rsw) << 4)) = pp;
        }
        lsum += psum;
      }
      // PV: single pass, counted lgkmcnt (pf reads + 16 tr-reads in flight)
      __builtin_amdgcn_s_setprio(1);
      {
        const __attribute__((address_space(3))) char* vb =
            (const __attribute__((address_space(3))) char*)((char*)Vs[cur]) + l * 8;
        int arow = w * 16 + lo;
        char* psb = (char*)Ps + arow * 128;
        const __attribute__((address_space(3))) char* pp0 =
            (const __attribute__((address_space(3))) char*)(psb + ((hi ^ (arow & 7)) << 4));
        const __attribute__((address_space(3))) char* pp1 =
            (const __attribute__((address_space(3))) char*)(psb + (((4 + hi) ^ (arow & 7)) << 4));
        bf16x8_t pf0, pf1;
        asm volatile("ds_read_b128 %0, %1" : "=v"(pf0) : "v"(pp0) : "memory");
        asm volatile("ds_read_b128 %0, %1" : "=v"(pf1) : "v"(pp1) : "memory");
        VFu u[8];
        TRR(u[0].w[0], vb, "0");    TRR(u[0].w[1], vb, "512");
        TRR(u[1].w[0], vb, "1024"); TRR(u[1].w[1], vb, "1536");
        TRR(u[2].w[0], vb, "2048"); TRR(u[2].w[1], vb, "2560");
        TRR(u[3].w[0], vb, "3072"); TRR(u[3].w[1], vb, "3584");
        TRR(u[4].w[0], vb, "4096"); TRR(u[4].w[1], vb, "4608");
        TRR(u[5].w[0], vb, "5120"); TRR(u[5].w[1], vb, "5632");
        TRR(u[6].w[0], vb, "6144"); TRR(u[6].w[1], vb, "6656");
        TRR(u[7].w[0], vb, "7168"); TRR(u[7].w[1], vb, "7680");
        asm volatile("s_waitcnt lgkmcnt(8)" ::: "memory");
        __builtin_amdgcn_sched_barrier(0);
        zacc[0] = __builtin_amdgcn_mfma_f32_16x16x32_bf16(pf0, u[0].v8, zacc[0], 0, 0, 0);
        zacc[1] = __builtin_amdgcn_mfma_f32_16x16x32_bf16(pf0, u[1].v8, zacc[1], 0, 0, 0);
        zacc[2] = __builtin_amdgcn_mfma_f32_16x16x32_bf16(pf0, u[2].v8, zacc[2], 0, 0, 0);
        zacc[3] = __builtin_amdgcn_mfma_f32_16x16x32_bf16(pf0, u[3].v8, zacc[3], 0, 0, 0);
        asm volatile("s_waitcnt lgkmcnt(0)" ::: "memory");
        __builtin_amdgcn_sched_barrier(0);
        zacc[0] = __builtin_amdgcn_mfma_f32_16x16x32_bf16(pf1, u[4].v8, zacc[0], 0, 0, 0);
        zacc[1] = __builtin_amdgcn_mfma_f32_16x16x32_bf16(pf1, u[5].v8, zacc[1], 0, 0, 0);
        zacc[2] = __builtin_amdgcn_mfma_f32_16x16x32_bf16(pf1, u[6].v8, zacc[2], 0, 0, 0);
        zacc[3] = __builtin_amdgcn_mfma_f32_16x16x32_bf16(pf1, u[7].v8, zacc[3], 0, 0, 0);
      }
      __builtin_amdgcn_s_setprio(0);
      __syncthreads();
    }

    // epilogue for this half: reduce lsum across hi-groups, normalize, store
    float lt = lsum;
    lt += __shfl_xor(lt, 16);
    lt += __shfl_xor(lt, 32);
    float inv = 1.0f / lt;
#pragma unroll
    for (int r = 0; r < 4; ++r) {
      float lv = __shfl(inv, hi * 4 + r);
      size_t row = (size_t)(b * 2048 + qbase + hi * 4 + r);
#pragma unroll
      for (int e0 = 0; e0 < 4; ++e0)
        Z[row * 1024 + h * 64 + e0 * 16 + lo] = (__bf16)(zacc[e0][r] * lv);
    }
    bufbase = (bufbase + ntH) & 1;  // half 1's tile 0 sits in the prefetched buffer
    __syncthreads();  // stores done; safe to reuse LDS next half
  }
#undef STAGE_KV
}

// ---------------- launch ----------------

extern "C" void kernel_launch(void* const* d_in, const int* in_sizes, int n_in,
                              void* d_out, int out_size, void* d_ws, size_t ws_size,
                              hipStream_t stream) {
  const float* x  = (const float*)d_in[0];
  const float* wq = (const float*)d_in[1];
  const float* wk = (const float*)d_in[2];
  const float* wv = (const float*)d_in[3];
  const float* wo = (const float*)d_in[4];
  const float* bq = (const float*)d_in[5];
  const float* bk = (const float*)d_in[6];
  const float* bv = (const float*)d_in[7];
  const float* bo = (const float*)d_in[8];
  float* out = (float*)d_out;

  char* ws = (char*)d_ws;
  __bf16* Xb   = (__bf16*)(ws);                //  8388608 B  [4096][1024]
  __bf16* WB1  = (__bf16*)(ws + 8388608);      //  6291456 B  [3072][1024]
  float*  B1   = (float*)(ws + 14680064);      //    12288 B  [3072]
  __bf16* WB2  = (__bf16*)(ws + 14692352);     //  2097152 B  [1024][1024]
  __bf16* QKVh = (__bf16*)(ws + 16789504);     // 25165824 B  [3][32][2048][64]
  __bf16* Zb   = Xb;                           // overlay: X dead after GEMM1

  k_prep<<<5132, 256, 0, stream>>>(x, wq, wk, wv, wo, bq, bk, bv, Xb, WB1, WB2, B1);
  k_gemm<__bf16, 1, 128, 64><<<1536, 256, 0, stream>>>(Xb, WB1, B1, QKVh, 3072, 1024);
  k_attn<<<512, 256, 0, stream>>>(QKVh, Zb);
  k_gemm<float, 0, 64, 64><<<1024, 256, 0, stream>>>(Zb, WB2, bo, out, 1024, 1024);
}

// Round 18
// 110.365 us; speedup vs baseline: 1.1426x; 1.0362x over previous
//
#include <hip/hip_runtime.h>

typedef float f32x4 __attribute__((ext_vector_type(4)));
typedef __bf16 bf16x8_t __attribute__((ext_vector_type(8)));
typedef __bf16 bf16x4_t __attribute__((ext_vector_type(4)));
typedef unsigned int u32x2 __attribute__((ext_vector_type(2)));

#define GLOAD16(gptr, lptr)                                                        \
  __builtin_amdgcn_global_load_lds((const __attribute__((address_space(1))) void*)(gptr), \
                                   (__attribute__((address_space(3))) void*)(lptr), 16, 0, 0)

__device__ inline float fexp2(float x) {
  float r;
  asm("v_exp_f32 %0, %1" : "=v"(r) : "v"(x));
  return r;
}

union VFu { bf16x8_t v8; u32x2 w[2]; };

#define TRR(d, B, OFF) \
  asm volatile("ds_read_b64_tr_b16 %0, %1 offset:" OFF : "=v"(d) : "v"(B))

// ---------------- merged prep kernel ----------------
__global__ __launch_bounds__(256) void k_prep(const float* __restrict__ x,
                                              const float* __restrict__ wq,
                                              const float* __restrict__ wk,
                                              const float* __restrict__ wv,
                                              const float* __restrict__ wo,
                                              const float* __restrict__ bq,
                                              const float* __restrict__ bk,
                                              const float* __restrict__ bv,
                                              __bf16* __restrict__ xb,
                                              __bf16* __restrict__ wb1,
                                              __bf16* __restrict__ wb2,
                                              float* __restrict__ b1) {
  __shared__ __bf16 tr[64][64];
  int bid = blockIdx.x, t = threadIdx.x;
  if (bid < 4096) {
    int i = bid * 256 + t;
    float4 a = reinterpret_cast<const float4*>(x)[i];
    bf16x4_t o;
    o[0] = (__bf16)a.x; o[1] = (__bf16)a.y; o[2] = (__bf16)a.z; o[3] = (__bf16)a.w;
    reinterpret_cast<bf16x4_t*>(xb)[i] = o;
  } else if (bid < 4864) {
    int k = bid - 4096;
    int dt = k & 15, h = (k >> 4) & 15, p = k >> 8;
    const float* W = (p == 0) ? wq : (p == 1) ? wk : wv;
#pragma unroll
    for (int i = 0; i < 4; ++i) {
      int fl = i * 1024 + t * 4;
      int dd = fl >> 6, e = fl & 63;
      float4 a = *reinterpret_cast<const float4*>(W + ((size_t)(h * 1024 + dt * 64 + dd) * 64 + e));
      tr[e + 0][dd] = (__bf16)a.x; tr[e + 1][dd] = (__bf16)a.y;
      tr[e + 2][dd] = (__bf16)a.z; tr[e + 3][dd] = (__bf16)a.w;
    }
    __syncthreads();
#pragma unroll
    for (int i = 0; i < 2; ++i) {
      int ch = i * 256 + t;
      int e = ch >> 3, c8 = ch & 7;
      *reinterpret_cast<bf16x8_t*>(wb1 + ((size_t)(p * 1024 + h * 64 + e) * 1024 + dt * 64 + c8 * 8)) =
          *reinterpret_cast<const bf16x8_t*>(&tr[e][c8 * 8]);
    }
  } else if (bid < 5120) {
    int k = bid - 4864;
    int nt = k & 15, h = k >> 4;
#pragma unroll
    for (int i = 0; i < 4; ++i) {
      int fl = i * 1024 + t * 4;
      int e = fl >> 6, nn = fl & 63;
      float4 a = *reinterpret_cast<const float4*>(wo + ((size_t)(h * 64 + e) * 1024 + nt * 64 + nn));
      tr[nn + 0][e] = (__bf16)a.x; tr[nn + 1][e] = (__bf16)a.y;
      tr[nn + 2][e] = (__bf16)a.z; tr[nn + 3][e] = (__bf16)a.w;
    }
    __syncthreads();
#pragma unroll
    for (int i = 0; i < 2; ++i) {
      int ch = i * 256 + t;
      int nn = ch >> 3, c8 = ch & 7;
      *reinterpret_cast<bf16x8_t*>(wb2 + ((size_t)(nt * 64 + nn) * 1024 + h * 64 + c8 * 8)) =
          *reinterpret_cast<const bf16x8_t*>(&tr[nn][c8 * 8]);
    }
  } else {
    int n = (bid - 5120) * 256 + t;
    if (n < 3072) {
      int p = n >> 10, he = n & 1023;
      const float* s = (p == 0) ? bq : (p == 1) ? bk : bv;
      b1[n] = s[he];
    }
  }
}

// ---------------- GEMM template: BK=64, tile MT x NT, XCD-chunked 1D grid ----
template <typename OutT, int MODE, int MT, int NT>
__global__ __launch_bounds__(256) void k_gemm(const __bf16* __restrict__ A,
                                              const __bf16* __restrict__ Bt,
                                              const float* __restrict__ bias,
                                              OutT* __restrict__ C, int N, int K) {
  __shared__ __bf16 As[MT * 64];
  __shared__ __bf16 Bs[NT * 64];
  constexpr int MI = MT / 32;
  constexpr int NR = NT / 32;
  constexpr int AI = MT / 32;
  constexpr int BI = NT / 32;
  int t = threadIdx.x, l = t & 63;
  int lo = l & 15, hi = l >> 4;
  int w = t >> 6;
  int bid = blockIdx.x;
  int xcd = bid & 7, loc = bid >> 3;
  int xc = N / NT;
  int rx = (int)gridDim.x / (8 * xc);
  int yy = loc / xc;
  int xx = loc - yy * xc;
  int m0 = (xcd * rx + yy) * MT, n0 = xx * NT;
  int wm = (w >> 1) * (MT / 2), wn = (w & 1) * (NT / 2);
  f32x4 acc[MI][NR] = {};
  for (int k0 = 0; k0 < K; k0 += 64) {
    __syncthreads();
#pragma unroll
    for (int it = 0; it < AI; ++it) {
      int idx = it * 256 + t;
      int row = idx >> 3, c = idx & 7;
      int cs = (c ^ (row & 7)) * 8;
      GLOAD16(A + (size_t)(m0 + row) * K + k0 + cs, (char*)As + (it * 256 + (t & ~63)) * 16);
    }
#pragma unroll
    for (int it = 0; it < BI; ++it) {
      int idx = it * 256 + t;
      int row = idx >> 3, c = idx & 7;
      int cs = (c ^ (row & 7)) * 8;
      GLOAD16(Bt + (size_t)(n0 + row) * K + k0 + cs, (char*)Bs + (it * 256 + (t & ~63)) * 16);
    }
    __syncthreads();
#pragma unroll
    for (int kc = 0; kc < 2; ++kc) {
      bf16x8_t af[MI], bfr[NR];
#pragma unroll
      for (int mi = 0; mi < MI; ++mi) {
        int row = wm + mi * 16 + lo;
        af[mi] = *reinterpret_cast<const bf16x8_t*>(
            (char*)As + row * 128 + (((kc * 4 + hi) ^ (row & 7)) << 4));
      }
#pragma unroll
      for (int ni = 0; ni < NR; ++ni) {
        int row = wn + ni * 16 + lo;
        bfr[ni] = *reinterpret_cast<const bf16x8_t*>(
            (char*)Bs + row * 128 + (((kc * 4 + hi) ^ (row & 7)) << 4));
      }
#pragma unroll
      for (int mi = 0; mi < MI; ++mi)
#pragma unroll
        for (int ni = 0; ni < NR; ++ni)
          acc[mi][ni] = __builtin_amdgcn_mfma_f32_16x16x32_bf16(af[mi], bfr[ni], acc[mi][ni], 0, 0, 0);
    }
  }
  float qs = (MODE == 1 && n0 < 1024) ? 0.18033688f : 1.0f;
#pragma unroll
  for (int ni = 0; ni < NR; ++ni) {
    int n = n0 + wn + ni * 16 + lo;
    float bv = bias[n];
    int p = n >> 10, hh = (n >> 6) & 15, e = n & 63;
#pragma unroll
    for (int mi = 0; mi < MI; ++mi) {
#pragma unroll
      for (int r = 0; r < 4; ++r) {
        int m = m0 + wm + mi * 16 + hi * 4 + r;
        if (MODE == 0) {
          C[(size_t)m * N + n] = (OutT)(acc[mi][ni][r] + bv);
        } else {
          int b = m >> 11, sr = m & 2047;
          C[(size_t)(p * 32 + b * 16 + hh) * 131072 + sr * 64 + e] =
              (OutT)((acc[mi][ni][r] + bv) * qs);
        }
      }
    }
  }
}

// ---------------- causal flash attention (v18: 128-kv super-tiles) ------------
// Block = pair (31-pr, pr) of 64-row q-groups, sequential halves with x-half
// prefetch. Each iter = 128 kv: one softmax pass, one barrier. LDS 80KB, 2/CU.
__global__ __launch_bounds__(256, 2) void k_attn(const __bf16* __restrict__ QKVh,
                                                 __bf16* __restrict__ Z) {
  __shared__ __bf16 Ks[2][128 * 64];  // super-tile: [64-tile 0][64-tile 1]
  __shared__ __bf16 Vs[2][128 * 64];  // subtiled for tr_b16 reads (per 64-tile)
  __shared__ __bf16 Ps[64 * 128];     // row stride 256B, 16-chunk XOR swizzle
  int t = threadIdx.x, l = t & 63, w = t >> 6;
  int lo = l & 15, hi = l >> 4;
  int bid = blockIdx.x;
  int xcd = bid & 7, kk = bid >> 3;
  int pr = kk & 15, bhl = kk >> 4;
  int bh = xcd * 4 + bhl;
  int b = bh >> 4, h = bh & 15;

  const __bf16* Qbase = QKVh + (size_t)bh * 131072;
  const __bf16* Kbase = QKVh + (size_t)(32 + bh) * 131072;
  const __bf16* Vbase = QKVh + (size_t)(64 + bh) * 131072;

  // per-thread staging source offsets (per 64-tile, tile-invariant)
  int kSrc[2], vSrc[2];
#pragma unroll
  for (int it = 0; it < 2; ++it) {
    int idx = it * 256 + t;
    int row = idx >> 3, c = idx & 7;
    kSrc[it] = row * 64 + ((c ^ (row & 7)) * 8);
    int kv = ((idx >> 1) & 3) | (((idx >> 5) & 1) << 2) | (((idx >> 3) & 3) << 3) |
             (((idx >> 8) & 1) << 5);
    int e0s = ((idx & 1) << 3) | (((idx >> 6) & 3) << 4);
    vSrc[it] = kv * 64 + e0s;
  }

// stage one 128-kv super-tile (two 64-tiles) into buffer buf
#define STAGE_KV(buf, sup)                                                              \
  {                                                                                     \
    GLOAD16(Kbase + (sup) * 8192 + kSrc[0], (char*)Ks[buf] + (t & ~63) * 16);           \
    GLOAD16(Kbase + (sup) * 8192 + kSrc[1], (char*)Ks[buf] + 4096 + (t & ~63) * 16);    \
    GLOAD16(Kbase + (sup) * 8192 + 4096 + kSrc[0], (char*)Ks[buf] + 8192 + (t & ~63) * 16); \
    GLOAD16(Kbase + (sup) * 8192 + 4096 + kSrc[1], (char*)Ks[buf] + 12288 + (t & ~63) * 16); \
    GLOAD16(Vbase + (sup) * 8192 + vSrc[0], (char*)Vs[buf] + (t & ~63) * 16);           \
    GLOAD16(Vbase + (sup) * 8192 + vSrc[1], (char*)Vs[buf] + 4096 + (t & ~63) * 16);    \
    GLOAD16(Vbase + (sup) * 8192 + 4096 + vSrc[0], (char*)Vs[buf] + 8192 + (t & ~63) * 16); \
    GLOAD16(Vbase + (sup) * 8192 + 4096 + vSrc[1], (char*)Vs[buf] + 12288 + (t & ~63) * 16); \
  }

  int bufbase = 0;
  STAGE_KV(0, 0);
  __syncthreads();

#pragma unroll 1
  for (int half = 0; half < 2; ++half) {
    int g = half ? pr : (31 - pr);   // long half first
    int qbase = g * 64 + w * 16;
    int nS = (g + 2) >> 1;           // ceil((g+1)/2) 128-kv super-tiles

    bf16x8_t qf[2];
    {
      const __bf16* qptr = Qbase + (qbase + lo) * 64;
      qf[0] = *reinterpret_cast<const bf16x8_t*>(qptr + hi * 8);
      qf[1] = *reinterpret_cast<const bf16x8_t*>(qptr + 32 + hi * 8);
    }

    f32x4 zacc[4] = {};
    float lsum = 0.f;
    float mrow = -1e30f;

    for (int sup = 0; sup < nS; ++sup) {
      int cur = (sup + bufbase) & 1, kv0 = sup * 128;
      bool havenext = (sup + 1 < nS);
      if (havenext) {
        STAGE_KV(cur ^ 1, sup + 1);
        __builtin_amdgcn_sched_barrier(0);
      } else if (half == 0) {
        STAGE_KV(cur ^ 1, 0);  // prefetch half 1's super 0
        __builtin_amdgcn_sched_barrier(0);
      }
      // QK^T swapped over 128 kv: s[jj][r] = S^T[kv = (jj>>2)*64+(jj&3)*16+hi*4+r][q=lo]
      f32x4 s[8] = {};
      __builtin_amdgcn_s_setprio(1);
#pragma unroll
      for (int jj = 0; jj < 8; ++jj) {
        int st = jj >> 2, cb = jj & 3;
        int krow = cb * 16 + lo;
        const char* kp = (const char*)Ks[cur] + st * 8192 + krow * 128;
        bf16x8_t kf0 = *reinterpret_cast<const bf16x8_t*>(kp + ((hi ^ (krow & 7)) << 4));
        bf16x8_t kf1 = *reinterpret_cast<const bf16x8_t*>(kp + (((4 + hi) ^ (krow & 7)) << 4));
        s[jj] = __builtin_amdgcn_mfma_f32_16x16x32_bf16(kf0, qf[0], s[jj], 0, 0, 0);
        s[jj] = __builtin_amdgcn_mfma_f32_16x16x32_bf16(kf1, qf[1], s[jj], 0, 0, 0);
      }
      __builtin_amdgcn_s_setprio(0);
      // softmax over 128 kv (exp2 domain), defer-max THR=8, per-lane lsum
      {
        int qabs = qbase + lo;
        if (sup == nS - 1) {  // wave-uniform: diagonal super only (covers overrun)
#pragma unroll
          for (int jj = 0; jj < 8; ++jj)
#pragma unroll
            for (int r = 0; r < 4; ++r)
              if (kv0 + (jj >> 2) * 64 + (jj & 3) * 16 + hi * 4 + r > qabs) s[jj][r] = -1e30f;
        }
        float mt = -1e30f;
#pragma unroll
        for (int jj = 0; jj < 8; ++jj) {
          float m01 = fmaxf(s[jj][0], s[jj][1]);
          float m23 = fmaxf(s[jj][2], s[jj][3]);
          mt = fmaxf(mt, fmaxf(m01, m23));
        }
        mt = fmaxf(mt, __shfl_xor(mt, 16));
        mt = fmaxf(mt, __shfl_xor(mt, 32));
        if (!__all(mt - mrow <= 8.0f)) {
          float mnew = fmaxf(mrow, mt);
          float alpha = fexp2(mrow - mnew);
          mrow = mnew;
          lsum *= alpha;
#pragma unroll
          for (int r = 0; r < 4; ++r) {
            float at = __shfl(alpha, hi * 4 + r);
#pragma unroll
            for (int e0 = 0; e0 < 4; ++e0) zacc[e0][r] *= at;
          }
        }
        float psum = 0.f;
        int prow = w * 16 + lo;
        char* prp = (char*)Ps + prow * 256 + (hi & 1) * 8;
        int rsw = prow & 15;
#pragma unroll
        for (int jj = 0; jj < 8; ++jj) {
          bf16x4_t pp;
#pragma unroll
          for (int r = 0; r < 4; ++r) {
            float p = fexp2(s[jj][r] - mrow);
            psum += p;
            pp[r] = (__bf16)p;
          }
          int chunk = (jj >> 2) * 8 + (jj & 3) * 2 + (hi >> 1);
          *reinterpret_cast<bf16x4_t*>(prp + ((chunk ^ rsw) << 4)) = pp;
        }
        lsum += psum;
      }
      // PV: two 64-kv halves, counted lgkmcnt each
      __builtin_amdgcn_s_setprio(1);
#pragma unroll
      for (int st = 0; st < 2; ++st) {
        const __attribute__((address_space(3))) char* vb =
            (const __attribute__((address_space(3))) char*)((char*)Vs[cur] + st * 8192) + l * 8;
        int arow = w * 16 + lo;
        char* psb = (char*)Ps + arow * 256;
        const __attribute__((address_space(3))) char* pp0 =
            (const __attribute__((address_space(3))) char*)(psb + (((st * 8 + hi) ^ (arow & 15)) << 4));
        const __attribute__((address_space(3))) char* pp1 =
            (const __attribute__((address_space(3))) char*)(psb + (((st * 8 + 4 + hi) ^ (arow & 15)) << 4));
        bf16x8_t pf0, pf1;
        asm volatile("ds_read_b128 %0, %1" : "=v"(pf0) : "v"(pp0) : "memory");
        asm volatile("ds_read_b128 %0, %1" : "=v"(pf1) : "v"(pp1) : "memory");
        VFu u[8];
        TRR(u[0].w[0], vb, "0");    TRR(u[0].w[1], vb, "512");
        TRR(u[1].w[0], vb, "1024"); TRR(u[1].w[1], vb, "1536");
        TRR(u[2].w[0], vb, "2048"); TRR(u[2].w[1], vb, "2560");
        TRR(u[3].w[0], vb, "3072"); TRR(u[3].w[1], vb, "3584");
        TRR(u[4].w[0], vb, "4096"); TRR(u[4].w[1], vb, "4608");
        TRR(u[5].w[0], vb, "5120"); TRR(u[5].w[1], vb, "5632");
        TRR(u[6].w[0], vb, "6144"); TRR(u[6].w[1], vb, "6656");
        TRR(u[7].w[0], vb, "7168"); TRR(u[7].w[1], vb, "7680");
        asm volatile("s_waitcnt lgkmcnt(8)" ::: "memory");
        __builtin_amdgcn_sched_barrier(0);
        zacc[0] = __builtin_amdgcn_mfma_f32_16x16x32_bf16(pf0, u[0].v8, zacc[0], 0, 0, 0);
        zacc[1] = __builtin_amdgcn_mfma_f32_16x16x32_bf16(pf0, u[1].v8, zacc[1], 0, 0, 0);
        zacc[2] = __builtin_amdgcn_mfma_f32_16x16x32_bf16(pf0, u[2].v8, zacc[2], 0, 0, 0);
        zacc[3] = __builtin_amdgcn_mfma_f32_16x16x32_bf16(pf0, u[3].v8, zacc[3], 0, 0, 0);
        asm volatile("s_waitcnt lgkmcnt(0)" ::: "memory");
        __builtin_amdgcn_sched_barrier(0);
        zacc[0] = __builtin_amdgcn_mfma_f32_16x16x32_bf16(pf1, u[4].v8, zacc[0], 0, 0, 0);
        zacc[1] = __builtin_amdgcn_mfma_f32_16x16x32_bf16(pf1, u[5].v8, zacc[1], 0, 0, 0);
        zacc[2] = __builtin_amdgcn_mfma_f32_16x16x32_bf16(pf1, u[6].v8, zacc[2], 0, 0, 0);
        zacc[3] = __builtin_amdgcn_mfma_f32_16x16x32_bf16(pf1, u[7].v8, zacc[3], 0, 0, 0);
      }
      __builtin_amdgcn_s_setprio(0);
      __syncthreads();
    }

    // epilogue for this half
    float lt = lsum;
    lt += __shfl_xor(lt, 16);
    lt += __shfl_xor(lt, 32);
    float inv = 1.0f / lt;
#pragma unroll
    for (int r = 0; r < 4; ++r) {
      float lv = __shfl(inv, hi * 4 + r);
      size_t row = (size_t)(b * 2048 + qbase + hi * 4 + r);
#pragma unroll
      for (int e0 = 0; e0 < 4; ++e0)
        Z[row * 1024 + h * 64 + e0 * 16 + lo] = (__bf16)(zacc[e0][r] * lv);
    }
    bufbase = (bufbase + nS) & 1;  // half 1's super 0 sits in the prefetched buffer
    __syncthreads();
  }
#undef STAGE_KV
}

// ---------------- launch ----------------

extern "C" void kernel_launch(void* const* d_in, const int* in_sizes, int n_in,
                              void* d_out, int out_size, void* d_ws, size_t ws_size,
                              hipStream_t stream) {
  const float* x  = (const float*)d_in[0];
  const float* wq = (const float*)d_in[1];
  const float* wk = (const float*)d_in[2];
  const float* wv = (const float*)d_in[3];
  const float* wo = (const float*)d_in[4];
  const float* bq = (const float*)d_in[5];
  const float* bk = (const float*)d_in[6];
  const float* bv = (const float*)d_in[7];
  const float* bo = (const float*)d_in[8];
  float* out = (float*)d_out;

  char* ws = (char*)d_ws;
  __bf16* Xb   = (__bf16*)(ws);                //  8388608 B  [4096][1024]
  __bf16* WB1  = (__bf16*)(ws + 8388608);      //  6291456 B  [3072][1024]
  float*  B1   = (float*)(ws + 14680064);      //    12288 B  [3072]
  __bf16* WB2  = (__bf16*)(ws + 14692352);     //  2097152 B  [1024][1024]
  __bf16* QKVh = (__bf16*)(ws + 16789504);     // 25165824 B  [3][32][2048][64]
  __bf16* Zb   = Xb;                           // overlay: X dead after GEMM1

  k_prep<<<5132, 256, 0, stream>>>(x, wq, wk, wv, wo, bq, bk, bv, Xb, WB1, WB2, B1);
  k_gemm<__bf16, 1, 128, 64><<<1536, 256, 0, stream>>>(Xb, WB1, B1, QKVh, 3072, 1024);
  k_attn<<<512, 256, 0, stream>>>(QKVh, Zb);
  k_gemm<float, 0, 64, 64><<<1024, 256, 0, stream>>>(Zb, WB2, bo, out, 1024, 1024);
}

// Round 19
// 105.612 us; speedup vs baseline: 1.1940x; 1.0450x over previous
//
#include <hip/hip_runtime.h>

typedef float f32x4 __attribute__((ext_vector_type(4)));
typedef __bf16 bf16x8_t __attribute__((ext_vector_type(8)));
typedef __bf16 bf16x4_t __attribute__((ext_vector_type(4)));
typedef unsigned int u32x2 __attribute__((ext_vector_type(2)));

#define GLOAD16(gptr, lptr)                                                        \
  __builtin_amdgcn_global_load_lds((const __attribute__((address_space(1))) void*)(gptr), \
                                   (__attribute__((address_space(3))) void*)(lptr), 16, 0, 0)

__device__ inline float fexp2(float x) {
  float r;
  asm("v_exp_f32 %0, %1" : "=v"(r) : "v"(x));
  return r;
}

union VFu { bf16x8_t v8; u32x2 w[2]; };

#define TRR(d, B, OFF) \
  asm volatile("ds_read_b64_tr_b16 %0, %1 offset:" OFF : "=v"(d) : "v"(B))

// ---------------- merged prep kernel ----------------
__global__ __launch_bounds__(256) void k_prep(const float* __restrict__ x,
                                              const float* __restrict__ wq,
                                              const float* __restrict__ wk,
                                              const float* __restrict__ wv,
                                              const float* __restrict__ wo,
                                              const float* __restrict__ bq,
                                              const float* __restrict__ bk,
                                              const float* __restrict__ bv,
                                              __bf16* __restrict__ xb,
                                              __bf16* __restrict__ wb1,
                                              __bf16* __restrict__ wb2,
                                              float* __restrict__ b1) {
  __shared__ __bf16 tr[64][64];
  int bid = blockIdx.x, t = threadIdx.x;
  if (bid < 4096) {
    int i = bid * 256 + t;
    float4 a = reinterpret_cast<const float4*>(x)[i];
    bf16x4_t o;
    o[0] = (__bf16)a.x; o[1] = (__bf16)a.y; o[2] = (__bf16)a.z; o[3] = (__bf16)a.w;
    reinterpret_cast<bf16x4_t*>(xb)[i] = o;
  } else if (bid < 4864) {
    int k = bid - 4096;
    int dt = k & 15, h = (k >> 4) & 15, p = k >> 8;
    const float* W = (p == 0) ? wq : (p == 1) ? wk : wv;
#pragma unroll
    for (int i = 0; i < 4; ++i) {
      int fl = i * 1024 + t * 4;
      int dd = fl >> 6, e = fl & 63;
      float4 a = *reinterpret_cast<const float4*>(W + ((size_t)(h * 1024 + dt * 64 + dd) * 64 + e));
      tr[e + 0][dd] = (__bf16)a.x; tr[e + 1][dd] = (__bf16)a.y;
      tr[e + 2][dd] = (__bf16)a.z; tr[e + 3][dd] = (__bf16)a.w;
    }
    __syncthreads();
#pragma unroll
    for (int i = 0; i < 2; ++i) {
      int ch = i * 256 + t;
      int e = ch >> 3, c8 = ch & 7;
      *reinterpret_cast<bf16x8_t*>(wb1 + ((size_t)(p * 1024 + h * 64 + e) * 1024 + dt * 64 + c8 * 8)) =
          *reinterpret_cast<const bf16x8_t*>(&tr[e][c8 * 8]);
    }
  } else if (bid < 5120) {
    int k = bid - 4864;
    int nt = k & 15, h = k >> 4;
#pragma unroll
    for (int i = 0; i < 4; ++i) {
      int fl = i * 1024 + t * 4;
      int e = fl >> 6, nn = fl & 63;
      float4 a = *reinterpret_cast<const float4*>(wo + ((size_t)(h * 64 + e) * 1024 + nt * 64 + nn));
      tr[nn + 0][e] = (__bf16)a.x; tr[nn + 1][e] = (__bf16)a.y;
      tr[nn + 2][e] = (__bf16)a.z; tr[nn + 3][e] = (__bf16)a.w;
    }
    __syncthreads();
#pragma unroll
    for (int i = 0; i < 2; ++i) {
      int ch = i * 256 + t;
      int nn = ch >> 3, c8 = ch & 7;
      *reinterpret_cast<bf16x8_t*>(wb2 + ((size_t)(nt * 64 + nn) * 1024 + h * 64 + c8 * 8)) =
          *reinterpret_cast<const bf16x8_t*>(&tr[nn][c8 * 8]);
    }
  } else {
    int n = (bid - 5120) * 256 + t;
    if (n < 3072) {
      int p = n >> 10, he = n & 1023;
      const float* s = (p == 0) ? bq : (p == 1) ? bk : bv;
      b1[n] = s[he];
    }
  }
}

// ---------------- GEMM: BK=64, tile MT x NT, 2D XCD rectangles -----------------
// XCDs arranged XM x XN over the tile grid; each owns (M/MT/XM) x (N/NT/XN)
// tiles -> per-XCD L2 working set = A + B panels both bounded.
template <typename OutT, int MODE, int MT, int NT, int XM, int XN, int MINW>
__global__ __launch_bounds__(256, MINW) void k_gemm(const __bf16* __restrict__ A,
                                                    const __bf16* __restrict__ Bt,
                                                    const float* __restrict__ bias,
                                                    OutT* __restrict__ C, int N, int K, int M) {
  __shared__ __bf16 As[MT * 64];
  __shared__ __bf16 Bs[NT * 64];
  constexpr int MI = MT / 32;
  constexpr int NR = NT / 32;
  constexpr int AI = MT / 32;
  constexpr int BI = NT / 32;
  int t = threadIdx.x, l = t & 63;
  int lo = l & 15, hi = l >> 4;
  int w = t >> 6;
  int bid = blockIdx.x;
  int xcd = bid & 7, loc = bid >> 3;
  int nc = N / NT / XN;            // n-tiles per XCD
  int mr = M / MT / XM;            // m-tiles per XCD
  int yy = loc / nc;
  int xx = loc - yy * nc;
  int m0 = ((xcd / XN) * mr + yy) * MT;
  int n0 = ((xcd % XN) * nc + xx) * NT;
  int wm = (w >> 1) * (MT / 2), wn = (w & 1) * (NT / 2);
  f32x4 acc[MI][NR] = {};
  for (int k0 = 0; k0 < K; k0 += 64) {
    __syncthreads();
#pragma unroll
    for (int it = 0; it < AI; ++it) {
      int idx = it * 256 + t;
      int row = idx >> 3, c = idx & 7;
      int cs = (c ^ (row & 7)) * 8;
      GLOAD16(A + (size_t)(m0 + row) * K + k0 + cs, (char*)As + (it * 256 + (t & ~63)) * 16);
    }
#pragma unroll
    for (int it = 0; it < BI; ++it) {
      int idx = it * 256 + t;
      int row = idx >> 3, c = idx & 7;
      int cs = (c ^ (row & 7)) * 8;
      GLOAD16(Bt + (size_t)(n0 + row) * K + k0 + cs, (char*)Bs + (it * 256 + (t & ~63)) * 16);
    }
    __syncthreads();
#pragma unroll
    for (int kc = 0; kc < 2; ++kc) {
      bf16x8_t af[MI], bfr[NR];
#pragma unroll
      for (int mi = 0; mi < MI; ++mi) {
        int row = wm + mi * 16 + lo;
        af[mi] = *reinterpret_cast<const bf16x8_t*>(
            (char*)As + row * 128 + (((kc * 4 + hi) ^ (row & 7)) << 4));
      }
#pragma unroll
      for (int ni = 0; ni < NR; ++ni) {
        int row = wn + ni * 16 + lo;
        bfr[ni] = *reinterpret_cast<const bf16x8_t*>(
            (char*)Bs + row * 128 + (((kc * 4 + hi) ^ (row & 7)) << 4));
      }
#pragma unroll
      for (int mi = 0; mi < MI; ++mi)
#pragma unroll
        for (int ni = 0; ni < NR; ++ni)
          acc[mi][ni] = __builtin_amdgcn_mfma_f32_16x16x32_bf16(af[mi], bfr[ni], acc[mi][ni], 0, 0, 0);
    }
  }
  float qs = (MODE == 1 && n0 < 1024) ? 0.18033688f : 1.0f;
#pragma unroll
  for (int ni = 0; ni < NR; ++ni) {
    int n = n0 + wn + ni * 16 + lo;
    float bv = bias[n];
    int p = n >> 10, hh = (n >> 6) & 15, e = n & 63;
#pragma unroll
    for (int mi = 0; mi < MI; ++mi) {
#pragma unroll
      for (int r = 0; r < 4; ++r) {
        int m = m0 + wm + mi * 16 + hi * 4 + r;
        if (MODE == 0) {
          C[(size_t)m * N + n] = (OutT)(acc[mi][ni][r] + bv);
        } else {
          int b = m >> 11, sr = m & 2047;
          C[(size_t)(p * 32 + b * 16 + hh) * 131072 + sr * 64 + e] =
              (OutT)((acc[mi][ni][r] + bv) * qs);
        }
      }
    }
  }
}

// ---------------- causal flash attention (v18: 128-kv super-tiles) ------------
// Block = pair (31-pr, pr) of 64-row q-groups, sequential halves with x-half
// prefetch. Each iter = 128 kv: one softmax pass, one barrier. LDS 80KB, 2/CU.
__global__ __launch_bounds__(256, 2) void k_attn(const __bf16* __restrict__ QKVh,
                                                 __bf16* __restrict__ Z) {
  __shared__ __bf16 Ks[2][128 * 64];  // super-tile: [64-tile 0][64-tile 1]
  __shared__ __bf16 Vs[2][128 * 64];  // subtiled for tr_b16 reads (per 64-tile)
  __shared__ __bf16 Ps[64 * 128];     // row stride 256B, 16-chunk XOR swizzle
  int t = threadIdx.x, l = t & 63, w = t >> 6;
  int lo = l & 15, hi = l >> 4;
  int bid = blockIdx.x;
  int xcd = bid & 7, kk = bid >> 3;
  int pr = kk & 15, bhl = kk >> 4;
  int bh = xcd * 4 + bhl;
  int b = bh >> 4, h = bh & 15;

  const __bf16* Qbase = QKVh + (size_t)bh * 131072;
  const __bf16* Kbase = QKVh + (size_t)(32 + bh) * 131072;
  const __bf16* Vbase = QKVh + (size_t)(64 + bh) * 131072;

  // per-thread staging source offsets (per 64-tile, tile-invariant)
  int kSrc[2], vSrc[2];
#pragma unroll
  for (int it = 0; it < 2; ++it) {
    int idx = it * 256 + t;
    int row = idx >> 3, c = idx & 7;
    kSrc[it] = row * 64 + ((c ^ (row & 7)) * 8);
    int kv = ((idx >> 1) & 3) | (((idx >> 5) & 1) << 2) | (((idx >> 3) & 3) << 3) |
             (((idx >> 8) & 1) << 5);
    int e0s = ((idx & 1) << 3) | (((idx >> 6) & 3) << 4);
    vSrc[it] = kv * 64 + e0s;
  }

// stage one 128-kv super-tile (two 64-tiles) into buffer buf
#define STAGE_KV(buf, sup)                                                              \
  {                                                                                     \
    GLOAD16(Kbase + (sup) * 8192 + kSrc[0], (char*)Ks[buf] + (t & ~63) * 16);           \
    GLOAD16(Kbase + (sup) * 8192 + kSrc[1], (char*)Ks[buf] + 4096 + (t & ~63) * 16);    \
    GLOAD16(Kbase + (sup) * 8192 + 4096 + kSrc[0], (char*)Ks[buf] + 8192 + (t & ~63) * 16); \
    GLOAD16(Kbase + (sup) * 8192 + 4096 + kSrc[1], (char*)Ks[buf] + 12288 + (t & ~63) * 16); \
    GLOAD16(Vbase + (sup) * 8192 + vSrc[0], (char*)Vs[buf] + (t & ~63) * 16);           \
    GLOAD16(Vbase + (sup) * 8192 + vSrc[1], (char*)Vs[buf] + 4096 + (t & ~63) * 16);    \
    GLOAD16(Vbase + (sup) * 8192 + 4096 + vSrc[0], (char*)Vs[buf] + 8192 + (t & ~63) * 16); \
    GLOAD16(Vbase + (sup) * 8192 + 4096 + vSrc[1], (char*)Vs[buf] + 12288 + (t & ~63) * 16); \
  }

  int bufbase = 0;
  STAGE_KV(0, 0);
  __syncthreads();

#pragma unroll 1
  for (int half = 0; half < 2; ++half) {
    int g = half ? pr : (31 - pr);   // long half first
    int qbase = g * 64 + w * 16;
    int nS = (g + 2) >> 1;           // ceil((g+1)/2) 128-kv super-tiles

    bf16x8_t qf[2];
    {
      const __bf16* qptr = Qbase + (qbase + lo) * 64;
      qf[0] = *reinterpret_cast<const bf16x8_t*>(qptr + hi * 8);
      qf[1] = *reinterpret_cast<const bf16x8_t*>(qptr + 32 + hi * 8);
    }

    f32x4 zacc[4] = {};
    float lsum = 0.f;
    float mrow = -1e30f;

    for (int sup = 0; sup < nS; ++sup) {
      int cur = (sup + bufbase) & 1, kv0 = sup * 128;
      bool havenext = (sup + 1 < nS);
      if (havenext) {
        STAGE_KV(cur ^ 1, sup + 1);
        __builtin_amdgcn_sched_barrier(0);
      } else if (half == 0) {
        STAGE_KV(cur ^ 1, 0);  // prefetch half 1's super 0
        __builtin_amdgcn_sched_barrier(0);
      }
      // QK^T swapped over 128 kv: s[jj][r] = S^T[kv = (jj>>2)*64+(jj&3)*16+hi*4+r][q=lo]
      f32x4 s[8] = {};
      __builtin_amdgcn_s_setprio(1);
#pragma unroll
      for (int jj = 0; jj < 8; ++jj) {
        int st = jj >> 2, cb = jj & 3;
        int krow = cb * 16 + lo;
        const char* kp = (const char*)Ks[cur] + st * 8192 + krow * 128;
        bf16x8_t kf0 = *reinterpret_cast<const bf16x8_t*>(kp + ((hi ^ (krow & 7)) << 4));
        bf16x8_t kf1 = *reinterpret_cast<const bf16x8_t*>(kp + (((4 + hi) ^ (krow & 7)) << 4));
        s[jj] = __builtin_amdgcn_mfma_f32_16x16x32_bf16(kf0, qf[0], s[jj], 0, 0, 0);
        s[jj] = __builtin_amdgcn_mfma_f32_16x16x32_bf16(kf1, qf[1], s[jj], 0, 0, 0);
      }
      __builtin_amdgcn_s_setprio(0);
      // softmax over 128 kv (exp2 domain), defer-max THR=8, per-lane lsum
      {
        int qabs = qbase + lo;
        if (sup == nS - 1) {  // wave-uniform: diagonal super only (covers overrun)
#pragma unroll
          for (int jj = 0; jj < 8; ++jj)
#pragma unroll
            for (int r = 0; r < 4; ++r)
              if (kv0 + (jj >> 2) * 64 + (jj & 3) * 16 + hi * 4 + r > qabs) s[jj][r] = -1e30f;
        }
        float mt = -1e30f;
#pragma unroll
        for (int jj = 0; jj < 8; ++jj) {
          float m01 = fmaxf(s[jj][0], s[jj][1]);
          float m23 = fmaxf(s[jj][2], s[jj][3]);
          mt = fmaxf(mt, fmaxf(m01, m23));
        }
        mt = fmaxf(mt, __shfl_xor(mt, 16));
        mt = fmaxf(mt, __shfl_xor(mt, 32));
        if (!__all(mt - mrow <= 8.0f)) {
          float mnew = fmaxf(mrow, mt);
          float alpha = fexp2(mrow - mnew);
          mrow = mnew;
          lsum *= alpha;
#pragma unroll
          for (int r = 0; r < 4; ++r) {
            float at = __shfl(alpha, hi * 4 + r);
#pragma unroll
            for (int e0 = 0; e0 < 4; ++e0) zacc[e0][r] *= at;
          }
        }
        float psum = 0.f;
        int prow = w * 16 + lo;
        char* prp = (char*)Ps + prow * 256 + (hi & 1) * 8;
        int rsw = prow & 15;
#pragma unroll
        for (int jj = 0; jj < 8; ++jj) {
          bf16x4_t pp;
#pragma unroll
          for (int r = 0; r < 4; ++r) {
            float p = fexp2(s[jj][r] - mrow);
            psum += p;
            pp[r] = (__bf16)p;
          }
          int chunk = (jj >> 2) * 8 + (jj & 3) * 2 + (hi >> 1);
          *reinterpret_cast<bf16x4_t*>(prp + ((chunk ^ rsw) << 4)) = pp;
        }
        lsum += psum;
      }
      // PV: two 64-kv halves, counted lgkmcnt each
      __builtin_amdgcn_s_setprio(1);
#pragma unroll
      for (int st = 0; st < 2; ++st) {
        const __attribute__((address_space(3))) char* vb =
            (const __attribute__((address_space(3))) char*)((char*)Vs[cur] + st * 8192) + l * 8;
        int arow = w * 16 + lo;
        char* psb = (char*)Ps + arow * 256;
        const __attribute__((address_space(3))) char* pp0 =
            (const __attribute__((address_space(3))) char*)(psb + (((st * 8 + hi) ^ (arow & 15)) << 4));
        const __attribute__((address_space(3))) char* pp1 =
            (const __attribute__((address_space(3))) char*)(psb + (((st * 8 + 4 + hi) ^ (arow & 15)) << 4));
        bf16x8_t pf0, pf1;
        asm volatile("ds_read_b128 %0, %1" : "=v"(pf0) : "v"(pp0) : "memory");
        asm volatile("ds_read_b128 %0, %1" : "=v"(pf1) : "v"(pp1) : "memory");
        VFu u[8];
        TRR(u[0].w[0], vb, "0");    TRR(u[0].w[1], vb, "512");
        TRR(u[1].w[0], vb, "1024"); TRR(u[1].w[1], vb, "1536");
        TRR(u[2].w[0], vb, "2048"); TRR(u[2].w[1], vb, "2560");
        TRR(u[3].w[0], vb, "3072"); TRR(u[3].w[1], vb, "3584");
        TRR(u[4].w[0], vb, "4096"); TRR(u[4].w[1], vb, "4608");
        TRR(u[5].w[0], vb, "5120"); TRR(u[5].w[1], vb, "5632");
        TRR(u[6].w[0], vb, "6144"); TRR(u[6].w[1], vb, "6656");
        TRR(u[7].w[0], vb, "7168"); TRR(u[7].w[1], vb, "7680");
        asm volatile("s_waitcnt lgkmcnt(8)" ::: "memory");
        __builtin_amdgcn_sched_barrier(0);
        zacc[0] = __builtin_amdgcn_mfma_f32_16x16x32_bf16(pf0, u[0].v8, zacc[0], 0, 0, 0);
        zacc[1] = __builtin_amdgcn_mfma_f32_16x16x32_bf16(pf0, u[1].v8, zacc[1], 0, 0, 0);
        zacc[2] = __builtin_amdgcn_mfma_f32_16x16x32_bf16(pf0, u[2].v8, zacc[2], 0, 0, 0);
        zacc[3] = __builtin_amdgcn_mfma_f32_16x16x32_bf16(pf0, u[3].v8, zacc[3], 0, 0, 0);
        asm volatile("s_waitcnt lgkmcnt(0)" ::: "memory");
        __builtin_amdgcn_sched_barrier(0);
        zacc[0] = __builtin_amdgcn_mfma_f32_16x16x32_bf16(pf1, u[4].v8, zacc[0], 0, 0, 0);
        zacc[1] = __builtin_amdgcn_mfma_f32_16x16x32_bf16(pf1, u[5].v8, zacc[1], 0, 0, 0);
        zacc[2] = __builtin_amdgcn_mfma_f32_16x16x32_bf16(pf1, u[6].v8, zacc[2], 0, 0, 0);
        zacc[3] = __builtin_amdgcn_mfma_f32_16x16x32_bf16(pf1, u[7].v8, zacc[3], 0, 0, 0);
      }
      __builtin_amdgcn_s_setprio(0);
      __syncthreads();
    }

    // epilogue for this half
    float lt = lsum;
    lt += __shfl_xor(lt, 16);
    lt += __shfl_xor(lt, 32);
    float inv = 1.0f / lt;
#pragma unroll
    for (int r = 0; r < 4; ++r) {
      float lv = __shfl(inv, hi * 4 + r);
      size_t row = (size_t)(b * 2048 + qbase + hi * 4 + r);
#pragma unroll
      for (int e0 = 0; e0 < 4; ++e0)
        Z[row * 1024 + h * 64 + e0 * 16 + lo] = (__bf16)(zacc[e0][r] * lv);
    }
    bufbase = (bufbase + nS) & 1;  // half 1's super 0 sits in the prefetched buffer
    __syncthreads();
  }
#undef STAGE_KV
}

// ---------------- launch ----------------

extern "C" void kernel_launch(void* const* d_in, const int* in_sizes, int n_in,
                              void* d_out, int out_size, void* d_ws, size_t ws_size,
                              hipStream_t stream) {
  const float* x  = (const float*)d_in[0];
  const float* wq = (const float*)d_in[1];
  const float* wk = (const float*)d_in[2];
  const float* wv = (const float*)d_in[3];
  const float* wo = (const float*)d_in[4];
  const float* bq = (const float*)d_in[5];
  const float* bk = (const float*)d_in[6];
  const float* bv = (const float*)d_in[7];
  const float* bo = (const float*)d_in[8];
  float* out = (float*)d_out;

  char* ws = (char*)d_ws;
  __bf16* Xb   = (__bf16*)(ws);                //  8388608 B  [4096][1024]
  __bf16* WB1  = (__bf16*)(ws + 8388608);      //  6291456 B  [3072][1024]
  float*  B1   = (float*)(ws + 14680064);      //    12288 B  [3072]
  __bf16* WB2  = (__bf16*)(ws + 14692352);     //  2097152 B  [1024][1024]
  __bf16* QKVh = (__bf16*)(ws + 16789504);     // 25165824 B  [3][32][2048][64]
  __bf16* Zb   = Xb;                           // overlay: X dead after GEMM1

  k_prep<<<5132, 256, 0, stream>>>(x, wq, wk, wv, wo, bq, bk, bv, Xb, WB1, WB2, B1);
  // GEMM1: 32m x 48n tiles; XCDs 4x2 -> 8m x 24n per XCD (A 2MB + B 3MB in L2)
  k_gemm<__bf16, 1, 128, 64, 4, 2, 6><<<1536, 256, 0, stream>>>(Xb, WB1, B1, QKVh, 3072, 1024, 4096);
  k_attn<<<512, 256, 0, stream>>>(QKVh, Zb);
  // GEMM2: 64m x 16n tiles; XCDs 8x1 -> 8m x 16n per XCD (A 1MB + B 2MB in L2)
  k_gemm<float, 0, 64, 64, 8, 1, 2><<<1024, 256, 0, stream>>>(Zb, WB2, bo, out, 1024, 1024, 4096);
}

// Round 20
// 103.468 us; speedup vs baseline: 1.2188x; 1.0207x over previous
//
#include <hip/hip_runtime.h>

typedef float f32x4 __attribute__((ext_vector_type(4)));
typedef __bf16 bf16x8_t __attribute__((ext_vector_type(8)));
typedef __bf16 bf16x4_t __attribute__((ext_vector_type(4)));
typedef unsigned int u32x2 __attribute__((ext_vector_type(2)));

#define GLOAD16(gptr, lptr)                                                        \
  __builtin_amdgcn_global_load_lds((const __attribute__((address_space(1))) void*)(gptr), \
                                   (__attribute__((address_space(3))) void*)(lptr), 16, 0, 0)

__device__ inline float fexp2(float x) {
  float r;
  asm("v_exp_f32 %0, %1" : "=v"(r) : "v"(x));
  return r;
}

union VFu { bf16x8_t v8; u32x2 w[2]; };

#define TRR(d, B, OFF) \
  asm volatile("ds_read_b64_tr_b16 %0, %1 offset:" OFF : "=v"(d) : "v"(B))

// ---------------- merged prep kernel ----------------
// blocks [0,2048): x fp32 -> bf16 (2 float4 per thread)
// blocks [2048,2816): packw1; [2816,3072): packw2; [3072,3084): bias concat
__global__ __launch_bounds__(256) void k_prep(const float* __restrict__ x,
                                              const float* __restrict__ wq,
                                              const float* __restrict__ wk,
                                              const float* __restrict__ wv,
                                              const float* __restrict__ wo,
                                              const float* __restrict__ bq,
                                              const float* __restrict__ bk,
                                              const float* __restrict__ bv,
                                              __bf16* __restrict__ xb,
                                              __bf16* __restrict__ wb1,
                                              __bf16* __restrict__ wb2,
                                              float* __restrict__ b1) {
  __shared__ __bf16 tr[64][64];
  int bid = blockIdx.x, t = threadIdx.x;
  if (bid < 2048) {
#pragma unroll
    for (int j = 0; j < 2; ++j) {
      int i = bid * 512 + j * 256 + t;
      float4 a = reinterpret_cast<const float4*>(x)[i];
      bf16x4_t o;
      o[0] = (__bf16)a.x; o[1] = (__bf16)a.y; o[2] = (__bf16)a.z; o[3] = (__bf16)a.w;
      reinterpret_cast<bf16x4_t*>(xb)[i] = o;
    }
  } else if (bid < 2816) {
    int k = bid - 2048;
    int dt = k & 15, h = (k >> 4) & 15, p = k >> 8;
    const float* W = (p == 0) ? wq : (p == 1) ? wk : wv;
#pragma unroll
    for (int i = 0; i < 4; ++i) {
      int fl = i * 1024 + t * 4;
      int dd = fl >> 6, e = fl & 63;
      float4 a = *reinterpret_cast<const float4*>(W + ((size_t)(h * 1024 + dt * 64 + dd) * 64 + e));
      tr[e + 0][dd] = (__bf16)a.x; tr[e + 1][dd] = (__bf16)a.y;
      tr[e + 2][dd] = (__bf16)a.z; tr[e + 3][dd] = (__bf16)a.w;
    }
    __syncthreads();
#pragma unroll
    for (int i = 0; i < 2; ++i) {
      int ch = i * 256 + t;
      int e = ch >> 3, c8 = ch & 7;
      *reinterpret_cast<bf16x8_t*>(wb1 + ((size_t)(p * 1024 + h * 64 + e) * 1024 + dt * 64 + c8 * 8)) =
          *reinterpret_cast<const bf16x8_t*>(&tr[e][c8 * 8]);
    }
  } else if (bid < 3072) {
    int k = bid - 2816;
    int nt = k & 15, h = k >> 4;
#pragma unroll
    for (int i = 0; i < 4; ++i) {
      int fl = i * 1024 + t * 4;
      int e = fl >> 6, nn = fl & 63;
      float4 a = *reinterpret_cast<const float4*>(wo + ((size_t)(h * 64 + e) * 1024 + nt * 64 + nn));
      tr[nn + 0][e] = (__bf16)a.x; tr[nn + 1][e] = (__bf16)a.y;
      tr[nn + 2][e] = (__bf16)a.z; tr[nn + 3][e] = (__bf16)a.w;
    }
    __syncthreads();
#pragma unroll
    for (int i = 0; i < 2; ++i) {
      int ch = i * 256 + t;
      int nn = ch >> 3, c8 = ch & 7;
      *reinterpret_cast<bf16x8_t*>(wb2 + ((size_t)(nt * 64 + nn) * 1024 + h * 64 + c8 * 8)) =
          *reinterpret_cast<const bf16x8_t*>(&tr[nn][c8 * 8]);
    }
  } else {
    int n = (bid - 3072) * 256 + t;
    if (n < 3072) {
      int p = n >> 10, he = n & 1023;
      const float* s = (p == 0) ? bq : (p == 1) ? bk : bv;
      b1[n] = s[he];
    }
  }
}

// ---------------- GEMM: BK=64, tile MT x NT, 2D XCD rectangles -----------------
template <typename OutT, int MODE, int MT, int NT, int XM, int XN, int MINW>
__global__ __launch_bounds__(256, MINW) void k_gemm(const __bf16* __restrict__ A,
                                                    const __bf16* __restrict__ Bt,
                                                    const float* __restrict__ bias,
                                                    OutT* __restrict__ C, int N, int K, int M) {
  __shared__ __bf16 As[MT * 64];
  __shared__ __bf16 Bs[NT * 64];
  constexpr int MI = MT / 32;
  constexpr int NR = NT / 32;
  constexpr int AI = MT / 32;
  constexpr int BI = NT / 32;
  int t = threadIdx.x, l = t & 63;
  int lo = l & 15, hi = l >> 4;
  int w = t >> 6;
  int bid = blockIdx.x;
  int xcd = bid & 7, loc = bid >> 3;
  int nc = N / NT / XN;
  int mr = M / MT / XM;
  int yy = loc / nc;
  int xx = loc - yy * nc;
  int m0 = ((xcd / XN) * mr + yy) * MT;
  int n0 = ((xcd % XN) * nc + xx) * NT;
  int wm = (w >> 1) * (MT / 2), wn = (w & 1) * (NT / 2);
  f32x4 acc[MI][NR] = {};
  for (int k0 = 0; k0 < K; k0 += 64) {
    __syncthreads();
#pragma unroll
    for (int it = 0; it < AI; ++it) {
      int idx = it * 256 + t;
      int row = idx >> 3, c = idx & 7;
      int cs = (c ^ (row & 7)) * 8;
      GLOAD16(A + (size_t)(m0 + row) * K + k0 + cs, (char*)As + (it * 256 + (t & ~63)) * 16);
    }
#pragma unroll
    for (int it = 0; it < BI; ++it) {
      int idx = it * 256 + t;
      int row = idx >> 3, c = idx & 7;
      int cs = (c ^ (row & 7)) * 8;
      GLOAD16(Bt + (size_t)(n0 + row) * K + k0 + cs, (char*)Bs + (it * 256 + (t & ~63)) * 16);
    }
    __syncthreads();
#pragma unroll
    for (int kc = 0; kc < 2; ++kc) {
      bf16x8_t af[MI], bfr[NR];
#pragma unroll
      for (int mi = 0; mi < MI; ++mi) {
        int row = wm + mi * 16 + lo;
        af[mi] = *reinterpret_cast<const bf16x8_t*>(
            (char*)As + row * 128 + (((kc * 4 + hi) ^ (row & 7)) << 4));
      }
#pragma unroll
      for (int ni = 0; ni < NR; ++ni) {
        int row = wn + ni * 16 + lo;
        bfr[ni] = *reinterpret_cast<const bf16x8_t*>(
            (char*)Bs + row * 128 + (((kc * 4 + hi) ^ (row & 7)) << 4));
      }
#pragma unroll
      for (int mi = 0; mi < MI; ++mi)
#pragma unroll
        for (int ni = 0; ni < NR; ++ni)
          acc[mi][ni] = __builtin_amdgcn_mfma_f32_16x16x32_bf16(af[mi], bfr[ni], acc[mi][ni], 0, 0, 0);
    }
  }
  float qs = (MODE == 1 && n0 < 1024) ? 0.18033688f : 1.0f;
#pragma unroll
  for (int ni = 0; ni < NR; ++ni) {
    int n = n0 + wn + ni * 16 + lo;
    float bv = bias[n];
    int p = n >> 10, hh = (n >> 6) & 15, e = n & 63;
#pragma unroll
    for (int mi = 0; mi < MI; ++mi) {
#pragma unroll
      for (int r = 0; r < 4; ++r) {
        int m = m0 + wm + mi * 16 + hi * 4 + r;
        if (MODE == 0) {
          C[(size_t)m * N + n] = (OutT)(acc[mi][ni][r] + bv);
        } else {
          int b = m >> 11, sr = m & 2047;
          C[(size_t)(p * 32 + b * 16 + hh) * 131072 + sr * 64 + e] =
              (OutT)((acc[mi][ni][r] + bv) * qs);
        }
      }
    }
  }
}

// ---------------- causal flash attention (v18 + max3 reduce) ------------------
__global__ __launch_bounds__(256, 2) void k_attn(const __bf16* __restrict__ QKVh,
                                                 __bf16* __restrict__ Z) {
  __shared__ __bf16 Ks[2][128 * 64];  // super-tile: [64-tile 0][64-tile 1]
  __shared__ __bf16 Vs[2][128 * 64];  // subtiled for tr_b16 reads (per 64-tile)
  __shared__ __bf16 Ps[64 * 128];     // row stride 256B, 16-chunk XOR swizzle
  int t = threadIdx.x, l = t & 63, w = t >> 6;
  int lo = l & 15, hi = l >> 4;
  int bid = blockIdx.x;
  int xcd = bid & 7, kk = bid >> 3;
  int pr = kk & 15, bhl = kk >> 4;
  int bh = xcd * 4 + bhl;
  int b = bh >> 4, h = bh & 15;

  const __bf16* Qbase = QKVh + (size_t)bh * 131072;
  const __bf16* Kbase = QKVh + (size_t)(32 + bh) * 131072;
  const __bf16* Vbase = QKVh + (size_t)(64 + bh) * 131072;

  int kSrc[2], vSrc[2];
#pragma unroll
  for (int it = 0; it < 2; ++it) {
    int idx = it * 256 + t;
    int row = idx >> 3, c = idx & 7;
    kSrc[it] = row * 64 + ((c ^ (row & 7)) * 8);
    int kv = ((idx >> 1) & 3) | (((idx >> 5) & 1) << 2) | (((idx >> 3) & 3) << 3) |
             (((idx >> 8) & 1) << 5);
    int e0s = ((idx & 1) << 3) | (((idx >> 6) & 3) << 4);
    vSrc[it] = kv * 64 + e0s;
  }

#define STAGE_KV(buf, sup)                                                              \
  {                                                                                     \
    GLOAD16(Kbase + (sup) * 8192 + kSrc[0], (char*)Ks[buf] + (t & ~63) * 16);           \
    GLOAD16(Kbase + (sup) * 8192 + kSrc[1], (char*)Ks[buf] + 4096 + (t & ~63) * 16);    \
    GLOAD16(Kbase + (sup) * 8192 + 4096 + kSrc[0], (char*)Ks[buf] + 8192 + (t & ~63) * 16); \
    GLOAD16(Kbase + (sup) * 8192 + 4096 + kSrc[1], (char*)Ks[buf] + 12288 + (t & ~63) * 16); \
    GLOAD16(Vbase + (sup) * 8192 + vSrc[0], (char*)Vs[buf] + (t & ~63) * 16);           \
    GLOAD16(Vbase + (sup) * 8192 + vSrc[1], (char*)Vs[buf] + 4096 + (t & ~63) * 16);    \
    GLOAD16(Vbase + (sup) * 8192 + 4096 + vSrc[0], (char*)Vs[buf] + 8192 + (t & ~63) * 16); \
    GLOAD16(Vbase + (sup) * 8192 + 4096 + vSrc[1], (char*)Vs[buf] + 12288 + (t & ~63) * 16); \
  }

  int bufbase = 0;
  STAGE_KV(0, 0);
  __syncthreads();

#pragma unroll 1
  for (int half = 0; half < 2; ++half) {
    int g = half ? pr : (31 - pr);   // long half first
    int qbase = g * 64 + w * 16;
    int nS = (g + 2) >> 1;

    bf16x8_t qf[2];
    {
      const __bf16* qptr = Qbase + (qbase + lo) * 64;
      qf[0] = *reinterpret_cast<const bf16x8_t*>(qptr + hi * 8);
      qf[1] = *reinterpret_cast<const bf16x8_t*>(qptr + 32 + hi * 8);
    }

    f32x4 zacc[4] = {};
    float lsum = 0.f;
    float mrow = -1e30f;

    for (int sup = 0; sup < nS; ++sup) {
      int cur = (sup + bufbase) & 1, kv0 = sup * 128;
      bool havenext = (sup + 1 < nS);
      if (havenext) {
        STAGE_KV(cur ^ 1, sup + 1);
        __builtin_amdgcn_sched_barrier(0);
      } else if (half == 0) {
        STAGE_KV(cur ^ 1, 0);  // prefetch half 1's super 0
        __builtin_amdgcn_sched_barrier(0);
      }
      // QK^T swapped over 128 kv
      f32x4 s[8] = {};
      __builtin_amdgcn_s_setprio(1);
#pragma unroll
      for (int jj = 0; jj < 8; ++jj) {
        int st = jj >> 2, cb = jj & 3;
        int krow = cb * 16 + lo;
        const char* kp = (const char*)Ks[cur] + st * 8192 + krow * 128;
        bf16x8_t kf0 = *reinterpret_cast<const bf16x8_t*>(kp + ((hi ^ (krow & 7)) << 4));
        bf16x8_t kf1 = *reinterpret_cast<const bf16x8_t*>(kp + (((4 + hi) ^ (krow & 7)) << 4));
        s[jj] = __builtin_amdgcn_mfma_f32_16x16x32_bf16(kf0, qf[0], s[jj], 0, 0, 0);
        s[jj] = __builtin_amdgcn_mfma_f32_16x16x32_bf16(kf1, qf[1], s[jj], 0, 0, 0);
      }
      __builtin_amdgcn_s_setprio(0);
      // softmax over 128 kv (exp2 domain), defer-max THR=8, per-lane lsum
      {
        int qabs = qbase + lo;
        if (sup == nS - 1) {
#pragma unroll
          for (int jj = 0; jj < 8; ++jj)
#pragma unroll
            for (int r = 0; r < 4; ++r)
              if (kv0 + (jj >> 2) * 64 + (jj & 3) * 16 + hi * 4 + r > qabs) s[jj][r] = -1e30f;
        }
        float mt = -1e30f;
#pragma unroll
        for (int jj = 0; jj < 8; ++jj) {
          // max3 pairs: clang fuses fmaxf(fmaxf(a,b),c) -> v_max3_f32
          float m3a = fmaxf(fmaxf(s[jj][0], s[jj][1]), s[jj][2]);
          mt = fmaxf(fmaxf(mt, m3a), s[jj][3]);
        }
        mt = fmaxf(mt, __shfl_xor(mt, 16));
        mt = fmaxf(mt, __shfl_xor(mt, 32));
        if (!__all(mt - mrow <= 8.0f)) {
          float mnew = fmaxf(mrow, mt);
          float alpha = fexp2(mrow - mnew);
          mrow = mnew;
          lsum *= alpha;
#pragma unroll
          for (int r = 0; r < 4; ++r) {
            float at = __shfl(alpha, hi * 4 + r);
#pragma unroll
            for (int e0 = 0; e0 < 4; ++e0) zacc[e0][r] *= at;
          }
        }
        float psum = 0.f;
        int prow = w * 16 + lo;
        char* prp = (char*)Ps + prow * 256 + (hi & 1) * 8;
        int rsw = prow & 15;
#pragma unroll
        for (int jj = 0; jj < 8; ++jj) {
          bf16x4_t pp;
#pragma unroll
          for (int r = 0; r < 4; ++r) {
            float p = fexp2(s[jj][r] - mrow);
            psum += p;
            pp[r] = (__bf16)p;
          }
          int chunk = (jj >> 2) * 8 + (jj & 3) * 2 + (hi >> 1);
          *reinterpret_cast<bf16x4_t*>(prp + ((chunk ^ rsw) << 4)) = pp;
        }
        lsum += psum;
      }
      // PV: two 64-kv halves, counted lgkmcnt each
      __builtin_amdgcn_s_setprio(1);
#pragma unroll
      for (int st = 0; st < 2; ++st) {
        const __attribute__((address_space(3))) char* vb =
            (const __attribute__((address_space(3))) char*)((char*)Vs[cur] + st * 8192) + l * 8;
        int arow = w * 16 + lo;
        char* psb = (char*)Ps + arow * 256;
        const __attribute__((address_space(3))) char* pp0 =
            (const __attribute__((address_space(3))) char*)(psb + (((st * 8 + hi) ^ (arow & 15)) << 4));
        const __attribute__((address_space(3))) char* pp1 =
            (const __attribute__((address_space(3))) char*)(psb + (((st * 8 + 4 + hi) ^ (arow & 15)) << 4));
        bf16x8_t pf0, pf1;
        asm volatile("ds_read_b128 %0, %1" : "=v"(pf0) : "v"(pp0) : "memory");
        asm volatile("ds_read_b128 %0, %1" : "=v"(pf1) : "v"(pp1) : "memory");
        VFu u[8];
        TRR(u[0].w[0], vb, "0");    TRR(u[0].w[1], vb, "512");
        TRR(u[1].w[0], vb, "1024"); TRR(u[1].w[1], vb, "1536");
        TRR(u[2].w[0], vb, "2048"); TRR(u[2].w[1], vb, "2560");
        TRR(u[3].w[0], vb, "3072"); TRR(u[3].w[1], vb, "3584");
        TRR(u[4].w[0], vb, "4096"); TRR(u[4].w[1], vb, "4608");
        TRR(u[5].w[0], vb, "5120"); TRR(u[5].w[1], vb, "5632");
        TRR(u[6].w[0], vb, "6144"); TRR(u[6].w[1], vb, "6656");
        TRR(u[7].w[0], vb, "7168"); TRR(u[7].w[1], vb, "7680");
        asm volatile("s_waitcnt lgkmcnt(8)" ::: "memory");
        __builtin_amdgcn_sched_barrier(0);
        zacc[0] = __builtin_amdgcn_mfma_f32_16x16x32_bf16(pf0, u[0].v8, zacc[0], 0, 0, 0);
        zacc[1] = __builtin_amdgcn_mfma_f32_16x16x32_bf16(pf0, u[1].v8, zacc[1], 0, 0, 0);
        zacc[2] = __builtin_amdgcn_mfma_f32_16x16x32_bf16(pf0, u[2].v8, zacc[2], 0, 0, 0);
        zacc[3] = __builtin_amdgcn_mfma_f32_16x16x32_bf16(pf0, u[3].v8, zacc[3], 0, 0, 0);
        asm volatile("s_waitcnt lgkmcnt(0)" ::: "memory");
        __builtin_amdgcn_sched_barrier(0);
        zacc[0] = __builtin_amdgcn_mfma_f32_16x16x32_bf16(pf1, u[4].v8, zacc[0], 0, 0, 0);
        zacc[1] = __builtin_amdgcn_mfma_f32_16x16x32_bf16(pf1, u[5].v8, zacc[1], 0, 0, 0);
        zacc[2] = __builtin_amdgcn_mfma_f32_16x16x32_bf16(pf1, u[6].v8, zacc[2], 0, 0, 0);
        zacc[3] = __builtin_amdgcn_mfma_f32_16x16x32_bf16(pf1, u[7].v8, zacc[3], 0, 0, 0);
      }
      __builtin_amdgcn_s_setprio(0);
      __syncthreads();
    }

    // epilogue for this half
    float lt = lsum;
    lt += __shfl_xor(lt, 16);
    lt += __shfl_xor(lt, 32);
    float inv = 1.0f / lt;
#pragma unroll
    for (int r = 0; r < 4; ++r) {
      float lv = __shfl(inv, hi * 4 + r);
      size_t row = (size_t)(b * 2048 + qbase + hi * 4 + r);
#pragma unroll
      for (int e0 = 0; e0 < 4; ++e0)
        Z[row * 1024 + h * 64 + e0 * 16 + lo] = (__bf16)(zacc[e0][r] * lv);
    }
    bufbase = (bufbase + nS) & 1;
    __syncthreads();
  }
#undef STAGE_KV
}

// ---------------- launch ----------------

extern "C" void kernel_launch(void* const* d_in, const int* in_sizes, int n_in,
                              void* d_out, int out_size, void* d_ws, size_t ws_size,
                              hipStream_t stream) {
  const float* x  = (const float*)d_in[0];
  const float* wq = (const float*)d_in[1];
  const float* wk = (const float*)d_in[2];
  const float* wv = (const float*)d_in[3];
  const float* wo = (const float*)d_in[4];
  const float* bq = (const float*)d_in[5];
  const float* bk = (const float*)d_in[6];
  const float* bv = (const float*)d_in[7];
  const float* bo = (const float*)d_in[8];
  float* out = (float*)d_out;

  char* ws = (char*)d_ws;
  __bf16* Xb   = (__bf16*)(ws);                //  8388608 B  [4096][1024]
  __bf16* WB1  = (__bf16*)(ws + 8388608);      //  6291456 B  [3072][1024]
  float*  B1   = (float*)(ws + 14680064);      //    12288 B  [3072]
  __bf16* WB2  = (__bf16*)(ws + 14692352);     //  2097152 B  [1024][1024]
  __bf16* QKVh = (__bf16*)(ws + 16789504);     // 25165824 B  [3][32][2048][64]
  __bf16* Zb   = Xb;                           // overlay: X dead after GEMM1

  k_prep<<<3084, 256, 0, stream>>>(x, wq, wk, wv, wo, bq, bk, bv, Xb, WB1, WB2, B1);
  // GEMM1: 32m x 48n tiles; XCDs 4x2 -> 8m x 24n per XCD
  k_gemm<__bf16, 1, 128, 64, 4, 2, 6><<<1536, 256, 0, stream>>>(Xb, WB1, B1, QKVh, 3072, 1024, 4096);
  k_attn<<<512, 256, 0, stream>>>(QKVh, Zb);
  // GEMM2: 64m x 16n tiles; XCDs 8x1
  k_gemm<float, 0, 64, 64, 8, 1, 2><<<1024, 256, 0, stream>>>(Zb, WB2, bo, out, 1024, 1024, 4096);
}